// Round 10
// baseline (503.811 us; speedup 1.0000x reference)
//
#include <hip/hip_runtime.h>
#include <hip/hip_bf16.h>

typedef __bf16 bf16_t;
typedef __bf16 bf16x8 __attribute__((ext_vector_type(8)));
typedef float f32x4 __attribute__((ext_vector_type(4)));

constexpr int Bz = 8, Lseq = 1024, Dm = 512, Hh = 8, DKd = 64;
constexpr int MTOK = Bz * Lseq;   // 8192 tokens
constexpr int NREL = 201;

// pos pre-scale: 0.125 (1/sqrt(dk)) * log2(e), folded so p = exp2(st*C + pos)
#define POS_C 0.18033688011112042f

__device__ inline float fexp2(float x) {
#if __has_builtin(__builtin_amdgcn_exp2f)
  return __builtin_amdgcn_exp2f(x);
#else
  return exp2f(x);
#endif
}
__device__ inline float b2f(unsigned short u) {
  return __builtin_bit_cast(float, (unsigned)u << 16);
}
__device__ inline unsigned pack2(float a, float b) {
  unsigned short ua = __builtin_bit_cast(unsigned short, (bf16_t)a);
  unsigned short ub = __builtin_bit_cast(unsigned short, (bf16_t)b);
  return (unsigned)ua | ((unsigned)ub << 16);
}

// ---------------- fp32 -> bf16 cast ----------------
__global__ __launch_bounds__(256) void k_cast(const float* __restrict__ s,
                                              bf16_t* __restrict__ d, int n) {
  int i = (blockIdx.x * 256 + threadIdx.x) * 4;
  if (i < n) {
    float4 v = *reinterpret_cast<const float4*>(s + i);
    d[i + 0] = (bf16_t)v.x;
    d[i + 1] = (bf16_t)v.y;
    d[i + 2] = (bf16_t)v.z;
    d[i + 3] = (bf16_t)v.w;
  }
}

// ---------------- y = A @ W^T  (A:[8192][512] bf16, W:[512][512] bf16) --------
// MODE 0: store bf16 head-major   out[(b*8+h)*1024+q][64]   (Qh / Kh)
// MODE 1: store bf16 head-transposed out[(b*8+h)*64+d][1024] (Vt)
// MODE 2: store fp32 row-major + residual add (pre-LN x)
template <int MODE>
__global__ __launch_bounds__(256) void k_gemm512(const bf16_t* __restrict__ A,
                                                 const bf16_t* __restrict__ W,
                                                 bf16_t* __restrict__ outb,
                                                 float* __restrict__ outf,
                                                 const float* __restrict__ resid) {
  const int lane = threadIdx.x & 63, w = threadIdx.x >> 6;
  const int lr = lane & 15, lg = lane >> 4;
  const int Rbase = blockIdx.y * 64 + (w >> 1) * 32;
  const int Cbase = blockIdx.x * 64 + (w & 1) * 32;

  f32x4 acc[2][2] = {};
  for (int k0 = 0; k0 < Dm; k0 += 32) {
    bf16x8 af[2], wf[2];
#pragma unroll
    for (int i = 0; i < 2; ++i)
      af[i] = *reinterpret_cast<const bf16x8*>(A + (size_t)(Rbase + i * 16 + lr) * Dm + k0 + lg * 8);
#pragma unroll
    for (int j = 0; j < 2; ++j)
      wf[j] = *reinterpret_cast<const bf16x8*>(W + (size_t)(Cbase + j * 16 + lr) * Dm + k0 + lg * 8);
#pragma unroll
    for (int i = 0; i < 2; ++i)
#pragma unroll
      for (int j = 0; j < 2; ++j)
        acc[i][j] = __builtin_amdgcn_mfma_f32_16x16x32_bf16(af[i], wf[j], acc[i][j], 0, 0, 0);
  }
#pragma unroll
  for (int i = 0; i < 2; ++i)
#pragma unroll
    for (int j = 0; j < 2; ++j)
#pragma unroll
      for (int r = 0; r < 4; ++r) {
        const int gr = Rbase + i * 16 + lg * 4 + r;  // token row
        const int gc = Cbase + j * 16 + lr;          // output col
        const float vv = acc[i][j][r];
        if (MODE == 0) {
          const int bb = gr >> 10, qq = gr & 1023, hh = gc >> 6, dd = gc & 63;
          outb[(((size_t)(bb * Hh + hh)) * Lseq + qq) * DKd + dd] = (bf16_t)vv;
        } else if (MODE == 1) {
          const int bb = gr >> 10, qq = gr & 1023, hh = gc >> 6, dd = gc & 63;
          outb[(((size_t)(bb * Hh + hh)) * DKd + dd) * Lseq + qq] = (bf16_t)vv;
        } else {
          const size_t idx = (size_t)gr * Dm + gc;
          outf[idx] = vv + resid[idx];
        }
      }
}

// ---------------- pos_dot, stored REVERSED and PRE-SCALED ---------------------
// pdr[q][j] = POS_C * (Qh[q] . rel_emb[200-j]);  in-band j = k - q + 100.
__global__ __launch_bounds__(256) void k_posdot(const bf16_t* __restrict__ Qh,
                                                const bf16_t* __restrict__ relb,
                                                bf16_t* __restrict__ posd) {
  const int lane = threadIdx.x & 63, w = threadIdx.x >> 6;
  const int lr = lane & 15, lg = lane >> 4;
  const int m0 = blockIdx.y * 64 + w * 16;
  const int n0 = blockIdx.x * 16;
  const int r = n0 + lr;

  bf16x8 a0 = *reinterpret_cast<const bf16x8*>(Qh + (size_t)(m0 + lr) * DKd + lg * 8);
  bf16x8 a1 = *reinterpret_cast<const bf16x8*>(Qh + (size_t)(m0 + lr) * DKd + 32 + lg * 8);
  bf16x8 b0 = {}, b1 = {};
  if (r < NREL) {
    b0 = *reinterpret_cast<const bf16x8*>(relb + (size_t)r * DKd + lg * 8);
    b1 = *reinterpret_cast<const bf16x8*>(relb + (size_t)r * DKd + 32 + lg * 8);
  }
  f32x4 acc = {};
  acc = __builtin_amdgcn_mfma_f32_16x16x32_bf16(a0, b0, acc, 0, 0, 0);
  acc = __builtin_amdgcn_mfma_f32_16x16x32_bf16(a1, b1, acc, 0, 0, 0);
#pragma unroll
  for (int rr = 0; rr < 4; ++rr) {
    const int row = m0 + lg * 4 + rr;
    const int col = n0 + lr;
    if (col < NREL)
      posd[(size_t)row * NREL + (200 - col)] = (bf16_t)(acc[rr] * POS_C);
  }
}

// ---------------- flash attention, no-max softmax, swapped QK^T ---------------
// QBLK=32 per unit; block = 4 waves = 1 unit x 4 k-quarters (256 k each);
// grid 2048 blocks. Explicit K-prefetch (next step's K loads issued before
// current step's compute) hides L2 latency. LDS: Pl (P transpose, 20.5KB)
// and Ml (merge, 25.5KB) share one buffer (Ml used after barrier, Pl dead).
// XCD-chunked swizzle keeps each XCD's K/V slice (8 bh = 2MB) L2-resident.
__global__ __launch_bounds__(256, 4) void k_attn(const bf16_t* __restrict__ Qh,
                                                 const bf16_t* __restrict__ Kh,
                                                 const bf16_t* __restrict__ Vt,
                                                 const bf16_t* __restrict__ posd,
                                                 bf16_t* __restrict__ attnb) {
  __shared__ float smemf[6528];   // max(Pl 20480B, Ml 26112B) = 26112B

  const int tid = threadIdx.x;
  const int wv = tid >> 6, lane = tid & 63;
  const int lr = lane & 15, lg = lane >> 4;
  // bijective chunked XCD swizzle (nwg=2048, 2048%8==0, chunk=256)
  const int gid = ((blockIdx.x & 7) << 8) | (blockIdx.x >> 3);
  const int bh = gid >> 5;
  const int qb = (gid & 31) << 5;             // 32-row q tile

  // per-wave Pl region: [2 par][2 t][16 row][20 col] uints = 1280 uints
  unsigned* Pw = reinterpret_cast<unsigned*>(smemf) + wv * 1280;

  const bf16_t* Qp = Qh + ((size_t)bh * Lseq + qb) * DKd;
  const bf16_t* Kp = Kh + (size_t)bh * Lseq * DKd;
  const bf16_t* Vp = Vt + (size_t)bh * DKd * Lseq;
  const unsigned short* pu =
      (const unsigned short*)posd + ((size_t)bh * Lseq + qb) * NREL;

  // per-lane pos row bases + band-edge constants (already scaled by POS_C)
  const unsigned short* rb[2] = {pu + (size_t)lr * NREL,
                                 pu + (size_t)(16 + lr) * NREL};
  float pe0[2], pe200[2];
#pragma unroll
  for (int t = 0; t < 2; ++t) {
    pe0[t] = b2f(rb[t][0]);       // k <= q-100 side
    pe200[t] = b2f(rb[t][200]);   // k >= q+100 side
  }

  // Q fragments (B-operand: lane&15 = q col, lg*8 = d dims, h = d-half)
  bf16x8 qf[2][2];
#pragma unroll
  for (int t = 0; t < 2; ++t)
#pragma unroll
    for (int h = 0; h < 2; ++h)
      qf[t][h] = *reinterpret_cast<const bf16x8*>(Qp + (size_t)(t * 16 + lr) * DKd + h * 32 + lg * 8);

  f32x4 Oacc[2][4] = {};
  float psum[2] = {0.f, 0.f};
  const int ldelta = lg * 4 - lr;

  auto loadK = [&](bf16x8 (&kf)[2][2], int k0) {
#pragma unroll
    for (int u = 0; u < 2; ++u)
#pragma unroll
      for (int h = 0; h < 2; ++h)
        kf[u][h] = *reinterpret_cast<const bf16x8*>(
            Kp + (size_t)(k0 + u * 16 + lr) * DKd + h * 32 + lg * 8);
  };

  auto process = [&](const bf16x8 (&kf)[2][2], int k0, int par) {
    // V fragments first: independent of the K->QK->softmax chain, so their
    // latency hides under it.
    bf16x8 vf[4];
#pragma unroll
    for (int f = 0; f < 4; ++f)
      vf[f] = *reinterpret_cast<const bf16x8*>(
          Vp + (size_t)(f * 16 + lr) * Lseq + k0 + lg * 8);

#pragma unroll
    for (int t = 0; t < 2; ++t) {
      const int Qt = qb + t * 16;
      f32x4 st[2];
#pragma unroll
      for (int u = 0; u < 2; ++u) {
        f32x4 a = {};
        a = __builtin_amdgcn_mfma_f32_16x16x32_bf16(kf[u][0], qf[t][0], a, 0, 0, 0);
        a = __builtin_amdgcn_mfma_f32_16x16x32_bf16(kf[u][1], qf[t][1], a, 0, 0, 0);
        st[u] = a;  // element: q = Qt+lr (col), k = k0+u*16+lg*4+r (row)
      }
      float p[2][4];
      if (k0 + 131 <= Qt) {            // whole step below band
#pragma unroll
        for (int u = 0; u < 2; ++u)
#pragma unroll
          for (int r = 0; r < 4; ++r)
            p[u][r] = fexp2(fmaf(st[u][r], POS_C, pe0[t]));
      } else if (k0 >= Qt + 115) {     // whole step above band
#pragma unroll
        for (int u = 0; u < 2; ++u)
#pragma unroll
          for (int r = 0; r < 4; ++r)
            p[u][r] = fexp2(fmaf(st[u][r], POS_C, pe200[t]));
      } else {                         // in-band: clamped gather (contiguous j)
#pragma unroll
        for (int u = 0; u < 2; ++u) {
          const int jb = k0 + u * 16 + 100 - Qt + ldelta;
#pragma unroll
          for (int r = 0; r < 4; ++r) {
            int j = jb + r;
            j = j < 0 ? 0 : (j > 200 ? 200 : j);
            p[u][r] = fexp2(fmaf(st[u][r], POS_C, b2f(rb[t][j])));
          }
        }
      }
#pragma unroll
      for (int u = 0; u < 2; ++u)
#pragma unroll
        for (int r = 0; r < 4; ++r) psum[t] += p[u][r];
      // pack to bf16, wave-private LDS transpose (D-layout -> B-frag layout)
#pragma unroll
      for (int u = 0; u < 2; ++u) {
        uint2 pk;
        pk.x = pack2(p[u][0], p[u][1]);
        pk.y = pack2(p[u][2], p[u][3]);
        *reinterpret_cast<uint2*>(&Pw[par * 640 + t * 320 + lr * 20 + u * 8 + lg * 2]) = pk;
      }
    }
    // PV: A = Vt fragment, B = P fragment read back from LDS
    bf16x8 pb[2];
#pragma unroll
    for (int t = 0; t < 2; ++t)
      pb[t] = *reinterpret_cast<const bf16x8*>(&Pw[par * 640 + t * 320 + lr * 20 + lg * 4]);
#pragma unroll
    for (int f = 0; f < 4; ++f)
#pragma unroll
      for (int t = 0; t < 2; ++t)
        Oacc[t][f] = __builtin_amdgcn_mfma_f32_16x16x32_bf16(vf[f], pb[t], Oacc[t][f], 0, 0, 0);
  };

  // software pipeline: K loads for step i+1 issued before processing step i
  const int kbase = wv * 256;
  bf16x8 kfA[2][2], kfB[2][2];
  loadK(kfA, kbase);
#pragma unroll
  for (int it2 = 0; it2 < 4; ++it2) {
    const int k0 = kbase + it2 * 64;
    loadK(kfB, k0 + 32);
    process(kfA, k0, 0);
    if (it2 < 3) loadK(kfA, k0 + 64);
    process(kfB, k0 + 32, 1);
  }

  // ---- merge the four k-quarters (no-max partials combine by pure addition) --
  __syncthreads();   // Pl region dead; reuse smem as Ml[3][64][34] floats
  float* Ml = smemf;
  if (wv) {
    float* m = Ml + ((wv - 1) * 64 + lane) * 34;
#pragma unroll
    for (int t = 0; t < 2; ++t)
#pragma unroll
      for (int f = 0; f < 4; ++f)
#pragma unroll
        for (int r = 0; r < 4; ++r) m[t * 16 + f * 4 + r] = Oacc[t][f][r];
    m[32] = psum[0];
    m[33] = psum[1];
  }
  __syncthreads();
  if (!wv) {
#pragma unroll
    for (int w2 = 0; w2 < 3; ++w2) {
      const float* m = Ml + (w2 * 64 + lane) * 34;
#pragma unroll
      for (int t = 0; t < 2; ++t) {
#pragma unroll
        for (int f = 0; f < 4; ++f)
#pragma unroll
          for (int r = 0; r < 4; ++r) Oacc[t][f][r] += m[t * 16 + f * 4 + r];
        psum[t] += m[32 + t];
      }
    }
    const int gb = bh >> 3, hh = bh & 7;
#pragma unroll
    for (int t = 0; t < 2; ++t) {
      float s = psum[t];
      s += __shfl_xor(s, 16);
      s += __shfl_xor(s, 32);
      const float inv = 1.0f / s;
      const int qg = qb + t * 16 + lr;
#pragma unroll
      for (int f = 0; f < 4; ++f) {
        uint2 ov;
        ov.x = pack2(Oacc[t][f][0] * inv, Oacc[t][f][1] * inv);
        ov.y = pack2(Oacc[t][f][2] * inv, Oacc[t][f][3] * inv);
        *reinterpret_cast<uint2*>(attnb + ((size_t)(gb * Lseq + qg)) * Dm + hh * DKd + f * 16 + lg * 4) = ov;
      }
    }
  }
}

// ---------------- row LayerNorm over D=512 ------------------------------------
__global__ __launch_bounds__(256) void k_ln(const float* __restrict__ y,
                                            const float* __restrict__ g,
                                            const float* __restrict__ be,
                                            float* __restrict__ out) {
  const int row = blockIdx.x * 4 + (threadIdx.x >> 6);
  const int lane = threadIdx.x & 63;
  const float* yp = y + (size_t)row * Dm + lane * 8;
  float4 v0 = *reinterpret_cast<const float4*>(yp);
  float4 v1 = *reinterpret_cast<const float4*>(yp + 4);
  float vv[8] = {v0.x, v0.y, v0.z, v0.w, v1.x, v1.y, v1.z, v1.w};
  float s = 0.f, s2 = 0.f;
#pragma unroll
  for (int j = 0; j < 8; ++j) { s += vv[j]; s2 += vv[j] * vv[j]; }
  for (int mk = 1; mk < 64; mk <<= 1) {
    s += __shfl_xor(s, mk, 64);
    s2 += __shfl_xor(s2, mk, 64);
  }
  const float mu = s * (1.0f / Dm);
  const float var = s2 * (1.0f / Dm) - mu * mu;
  const float inv = rsqrtf(var + 1e-6f);
  float* op = out + (size_t)row * Dm + lane * 8;
  const float* gp = g + lane * 8;
  const float* bp = be + lane * 8;
#pragma unroll
  for (int j = 0; j < 8; ++j) op[j] = (vv[j] - mu) * inv * gp[j] + bp[j];
}

// ------------------------------------------------------------------------------
extern "C" void kernel_launch(void* const* d_in, const int* in_sizes, int n_in,
                              void* d_out, int out_size, void* d_ws, size_t ws_size,
                              hipStream_t stream) {
  const float* q   = (const float*)d_in[0];
  const float* k   = (const float*)d_in[1];
  const float* v   = (const float*)d_in[2];
  const float* Wq  = (const float*)d_in[3];
  const float* Wk  = (const float*)d_in[4];
  const float* Wv  = (const float*)d_in[5];
  const float* Wfc = (const float*)d_in[6];
  const float* rel = (const float*)d_in[7];
  const float* gam = (const float*)d_in[8];
  const float* bet = (const float*)d_in[9];

  char* ws = (char*)d_ws;
  size_t off = 0;
  auto take = [&](size_t bytes) {
    char* p = ws + off;
    off += (bytes + 255) & ~(size_t)255;
    return p;
  };
  bf16_t* wqb  = (bf16_t*)take((size_t)Dm * Dm * 2);
  bf16_t* wkb  = (bf16_t*)take((size_t)Dm * Dm * 2);
  bf16_t* wvb  = (bf16_t*)take((size_t)Dm * Dm * 2);
  bf16_t* wfcb = (bf16_t*)take((size_t)Dm * Dm * 2);
  bf16_t* relb = (bf16_t*)take((size_t)NREL * DKd * 2);
  bf16_t* qb   = (bf16_t*)take((size_t)MTOK * Dm * 2);
  bf16_t* kb   = (bf16_t*)take((size_t)MTOK * Dm * 2);
  bf16_t* vb   = (bf16_t*)take((size_t)MTOK * Dm * 2);
  bf16_t* Qhp  = (bf16_t*)take((size_t)MTOK * Dm * 2);
  bf16_t* Khp  = (bf16_t*)take((size_t)MTOK * Dm * 2);
  bf16_t* Vtp  = (bf16_t*)take((size_t)MTOK * Dm * 2);
  bf16_t* posd = (bf16_t*)take((size_t)Bz * Hh * Lseq * NREL * 2);
  bf16_t* attnb= (bf16_t*)take((size_t)MTOK * Dm * 2);
  float*  yf   = (float*)take((size_t)MTOK * Dm * 4);

  auto cast = [&](const float* s, bf16_t* d, int n) {
    k_cast<<<dim3((n / 4 + 255) / 256), 256, 0, stream>>>(s, d, n);
  };
  cast(q, qb, MTOK * Dm);
  cast(k, kb, MTOK * Dm);
  cast(v, vb, MTOK * Dm);
  cast(Wq, wqb, Dm * Dm);
  cast(Wk, wkb, Dm * Dm);
  cast(Wv, wvb, Dm * Dm);
  cast(Wfc, wfcb, Dm * Dm);
  cast(rel, relb, NREL * DKd);

  dim3 gg(Dm / 64, MTOK / 64);
  k_gemm512<0><<<gg, 256, 0, stream>>>(qb, wqb, Qhp, nullptr, nullptr);
  k_gemm512<0><<<gg, 256, 0, stream>>>(kb, wkb, Khp, nullptr, nullptr);
  k_gemm512<1><<<gg, 256, 0, stream>>>(vb, wvb, Vtp, nullptr, nullptr);
  k_posdot<<<dim3(13, MTOK / 64), 256, 0, stream>>>(Qhp, relb, posd);
  k_attn<<<dim3(2048), 256, 0, stream>>>(Qhp, Khp, Vtp, posd, attnb);
  k_gemm512<2><<<gg, 256, 0, stream>>>(attnb, wfcb, nullptr, yf, q);
  k_ln<<<dim3(MTOK / 4), 256, 0, stream>>>(yf, gam, bet, (float*)d_out);
}

// Round 11
// 308.650 us; speedup vs baseline: 1.6323x; 1.6323x over previous
//
#include <hip/hip_runtime.h>
#include <hip/hip_bf16.h>

typedef __bf16 bf16_t;
typedef __bf16 bf16x8 __attribute__((ext_vector_type(8)));
typedef float f32x4 __attribute__((ext_vector_type(4)));

constexpr int Bz = 8, Lseq = 1024, Dm = 512, Hh = 8, DKd = 64;
constexpr int MTOK = Bz * Lseq;   // 8192 tokens
constexpr int NREL = 201;

// pos pre-scale: 0.125 (1/sqrt(dk)) * log2(e), folded so p = exp2(st*C + pos)
#define POS_C 0.18033688011112042f

__device__ inline float fexp2(float x) {
#if __has_builtin(__builtin_amdgcn_exp2f)
  return __builtin_amdgcn_exp2f(x);
#else
  return exp2f(x);
#endif
}
__device__ inline float b2f(unsigned short u) {
  return __builtin_bit_cast(float, (unsigned)u << 16);
}
__device__ inline unsigned pack2(float a, float b) {
  unsigned short ua = __builtin_bit_cast(unsigned short, (bf16_t)a);
  unsigned short ub = __builtin_bit_cast(unsigned short, (bf16_t)b);
  return (unsigned)ua | ((unsigned)ub << 16);
}
__device__ inline bf16x8 cvt8(const float* __restrict__ p) {
  float4 x = *reinterpret_cast<const float4*>(p);
  float4 y = *reinterpret_cast<const float4*>(p + 4);
  bf16x8 r;
  r[0] = (bf16_t)x.x; r[1] = (bf16_t)x.y; r[2] = (bf16_t)x.z; r[3] = (bf16_t)x.w;
  r[4] = (bf16_t)y.x; r[5] = (bf16_t)y.y; r[6] = (bf16_t)y.z; r[7] = (bf16_t)y.w;
  return r;
}

// ---------------- one-launch cast of Wq,Wk,Wv,Wfc (256K each) + rel (12864) ---
__global__ __launch_bounds__(256) void k_castw(
    const float* __restrict__ s0, const float* __restrict__ s1,
    const float* __restrict__ s2, const float* __restrict__ s3,
    const float* __restrict__ s4, bf16_t* __restrict__ d0,
    bf16_t* __restrict__ d1, bf16_t* __restrict__ d2, bf16_t* __restrict__ d3,
    bf16_t* __restrict__ d4) {
  const int y = blockIdx.y;
  const float* s = y == 0 ? s0 : y == 1 ? s1 : y == 2 ? s2 : y == 3 ? s3 : s4;
  bf16_t* d = y == 0 ? d0 : y == 1 ? d1 : y == 2 ? d2 : y == 3 ? d3 : d4;
  const int n = y < 4 ? Dm * Dm : NREL * DKd;
  int i = (blockIdx.x * 256 + threadIdx.x) * 4;
  if (i + 3 < n) {
    float4 v = *reinterpret_cast<const float4*>(s + i);
    d[i + 0] = (bf16_t)v.x;
    d[i + 1] = (bf16_t)v.y;
    d[i + 2] = (bf16_t)v.z;
    d[i + 3] = (bf16_t)v.w;
  } else if (i < n) {
    for (; i < n; ++i) d[i] = (bf16_t)s[i];
  }
}

// ---------------- fused-cast projections: y = (fp32 A) @ W^T -----------------
// blockIdx.z: 0 -> Q (head-major), 1 -> K (head-major), 2 -> V (head-transposed)
__global__ __launch_bounds__(256) void k_proj(
    const float* __restrict__ Aq, const float* __restrict__ Ak,
    const float* __restrict__ Av, const bf16_t* __restrict__ Wq_,
    const bf16_t* __restrict__ Wk_, const bf16_t* __restrict__ Wv_,
    bf16_t* __restrict__ Qo, bf16_t* __restrict__ Ko, bf16_t* __restrict__ Vo) {
  const int which = blockIdx.z;
  const float* A = which == 0 ? Aq : which == 1 ? Ak : Av;
  const bf16_t* W = which == 0 ? Wq_ : which == 1 ? Wk_ : Wv_;
  bf16_t* outb = which == 0 ? Qo : which == 1 ? Ko : Vo;

  const int lane = threadIdx.x & 63, w = threadIdx.x >> 6;
  const int lr = lane & 15, lg = lane >> 4;
  const int Rbase = blockIdx.y * 64 + (w >> 1) * 32;
  const int Cbase = blockIdx.x * 64 + (w & 1) * 32;

  f32x4 acc[2][2] = {};
  for (int k0 = 0; k0 < Dm; k0 += 32) {
    bf16x8 af[2], wf[2];
#pragma unroll
    for (int i = 0; i < 2; ++i)
      af[i] = cvt8(A + (size_t)(Rbase + i * 16 + lr) * Dm + k0 + lg * 8);
#pragma unroll
    for (int j = 0; j < 2; ++j)
      wf[j] = *reinterpret_cast<const bf16x8*>(W + (size_t)(Cbase + j * 16 + lr) * Dm + k0 + lg * 8);
#pragma unroll
    for (int i = 0; i < 2; ++i)
#pragma unroll
      for (int j = 0; j < 2; ++j)
        acc[i][j] = __builtin_amdgcn_mfma_f32_16x16x32_bf16(af[i], wf[j], acc[i][j], 0, 0, 0);
  }
#pragma unroll
  for (int i = 0; i < 2; ++i)
#pragma unroll
    for (int j = 0; j < 2; ++j)
#pragma unroll
      for (int r = 0; r < 4; ++r) {
        const int gr = Rbase + i * 16 + lg * 4 + r;  // token row
        const int gc = Cbase + j * 16 + lr;          // output col
        const int bb = gr >> 10, qq = gr & 1023, hh = gc >> 6, dd = gc & 63;
        const bf16_t vv = (bf16_t)acc[i][j][r];
        if (which < 2)
          outb[(((size_t)(bb * Hh + hh)) * Lseq + qq) * DKd + dd] = vv;
        else
          outb[(((size_t)(bb * Hh + hh)) * DKd + dd) * Lseq + qq] = vv;
      }
}

// ---------------- fc GEMM: y = attnb @ Wfc^T + resid (fp32 out) ---------------
__global__ __launch_bounds__(256) void k_fc(const bf16_t* __restrict__ A,
                                            const bf16_t* __restrict__ W,
                                            float* __restrict__ outf,
                                            const float* __restrict__ resid) {
  const int lane = threadIdx.x & 63, w = threadIdx.x >> 6;
  const int lr = lane & 15, lg = lane >> 4;
  const int Rbase = blockIdx.y * 64 + (w >> 1) * 32;
  const int Cbase = blockIdx.x * 64 + (w & 1) * 32;

  f32x4 acc[2][2] = {};
  for (int k0 = 0; k0 < Dm; k0 += 32) {
    bf16x8 af[2], wf[2];
#pragma unroll
    for (int i = 0; i < 2; ++i)
      af[i] = *reinterpret_cast<const bf16x8*>(A + (size_t)(Rbase + i * 16 + lr) * Dm + k0 + lg * 8);
#pragma unroll
    for (int j = 0; j < 2; ++j)
      wf[j] = *reinterpret_cast<const bf16x8*>(W + (size_t)(Cbase + j * 16 + lr) * Dm + k0 + lg * 8);
#pragma unroll
    for (int i = 0; i < 2; ++i)
#pragma unroll
      for (int j = 0; j < 2; ++j)
        acc[i][j] = __builtin_amdgcn_mfma_f32_16x16x32_bf16(af[i], wf[j], acc[i][j], 0, 0, 0);
  }
#pragma unroll
  for (int i = 0; i < 2; ++i)
#pragma unroll
    for (int j = 0; j < 2; ++j)
#pragma unroll
      for (int r = 0; r < 4; ++r) {
        const int gr = Rbase + i * 16 + lg * 4 + r;
        const int gc = Cbase + j * 16 + lr;
        const size_t idx = (size_t)gr * Dm + gc;
        outf[idx] = acc[i][j][r] + resid[idx];
      }
}

// ---------------- pos_dot, stored REVERSED and PRE-SCALED ---------------------
// pdr[q][j] = POS_C * (Qh[q] . rel_emb[200-j]);  in-band j = k - q + 100.
__global__ __launch_bounds__(256) void k_posdot(const bf16_t* __restrict__ Qh,
                                                const bf16_t* __restrict__ relb,
                                                bf16_t* __restrict__ posd) {
  const int lane = threadIdx.x & 63, w = threadIdx.x >> 6;
  const int lr = lane & 15, lg = lane >> 4;
  const int m0 = blockIdx.y * 64 + w * 16;
  const int n0 = blockIdx.x * 16;
  const int r = n0 + lr;

  bf16x8 a0 = *reinterpret_cast<const bf16x8*>(Qh + (size_t)(m0 + lr) * DKd + lg * 8);
  bf16x8 a1 = *reinterpret_cast<const bf16x8*>(Qh + (size_t)(m0 + lr) * DKd + 32 + lg * 8);
  bf16x8 b0 = {}, b1 = {};
  if (r < NREL) {
    b0 = *reinterpret_cast<const bf16x8*>(relb + (size_t)r * DKd + lg * 8);
    b1 = *reinterpret_cast<const bf16x8*>(relb + (size_t)r * DKd + 32 + lg * 8);
  }
  f32x4 acc = {};
  acc = __builtin_amdgcn_mfma_f32_16x16x32_bf16(a0, b0, acc, 0, 0, 0);
  acc = __builtin_amdgcn_mfma_f32_16x16x32_bf16(a1, b1, acc, 0, 0, 0);
#pragma unroll
  for (int rr = 0; rr < 4; ++rr) {
    const int row = m0 + lg * 4 + rr;
    const int col = n0 + lr;
    if (col < NREL)
      posd[(size_t)row * NREL + (200 - col)] = (bf16_t)(acc[rr] * POS_C);
  }
}

// ---------------- flash attention (r7-verified: 117us, no spill) --------------
// QBLK=32, 2-way k-split, wave-private padded-LDS P transpose, XCD swizzle.
__global__ __launch_bounds__(256, 4) void k_attn(const bf16_t* __restrict__ Qh,
                                                 const bf16_t* __restrict__ Kh,
                                                 const bf16_t* __restrict__ Vt,
                                                 const bf16_t* __restrict__ posd,
                                                 bf16_t* __restrict__ attnb) {
  __shared__ unsigned Pl[4][2][16][20];   // per-wave P transpose, padded rows
  __shared__ float Ml[2][64][35];         // k-split merge buffer

  const int tid = threadIdx.x;
  const int wv = tid >> 6, lane = tid & 63;
  const int lr = lane & 15, lg = lane >> 4;
  const int pair = wv >> 1, kh = wv & 1;
  // bijective chunked XCD swizzle (nwg=1024, 1024%8==0)
  const int bid = ((blockIdx.x & 7) << 7) | (blockIdx.x >> 3);
  const int gid = bid * 2 + pair;             // 2048 units
  const int bh = gid >> 5;
  const int qb = (gid & 31) << 5;             // 32-row q tile

  const bf16_t* Qp = Qh + ((size_t)bh * Lseq + qb) * DKd;
  const bf16_t* Kp = Kh + (size_t)bh * Lseq * DKd;
  const bf16_t* Vp = Vt + (size_t)bh * DKd * Lseq;
  const unsigned short* pu =
      (const unsigned short*)posd + ((size_t)bh * Lseq + qb) * NREL;

  // per-lane pos row bases + band-edge constants (already scaled by POS_C)
  const unsigned short* rb[2] = {pu + (size_t)lr * NREL,
                                 pu + (size_t)(16 + lr) * NREL};
  float pe0[2], pe200[2];
#pragma unroll
  for (int t = 0; t < 2; ++t) {
    pe0[t] = b2f(rb[t][0]);       // k <= q-100 side
    pe200[t] = b2f(rb[t][200]);   // k >= q+100 side
  }

  // Q fragments (B-operand: lane&15 = q col, lg*8 = d dims, h = d-half)
  bf16x8 qf[2][2];
#pragma unroll
  for (int t = 0; t < 2; ++t)
#pragma unroll
    for (int h = 0; h < 2; ++h)
      qf[t][h] = *reinterpret_cast<const bf16x8*>(Qp + (size_t)(t * 16 + lr) * DKd + h * 32 + lg * 8);

  f32x4 Oacc[2][4] = {};
  float psum[2] = {0.f, 0.f};
  const int ldelta = lg * 4 - lr;

#pragma unroll 2
  for (int k0 = kh * 512; k0 < kh * 512 + 512; k0 += 32) {
    // K fragments (A-operand: lane&15 = k row, lg*8 = d dims)
    bf16x8 kf[2][2];
#pragma unroll
    for (int u = 0; u < 2; ++u)
#pragma unroll
      for (int h = 0; h < 2; ++h)
        kf[u][h] = *reinterpret_cast<const bf16x8*>(Kp + (size_t)(k0 + u * 16 + lr) * DKd + h * 32 + lg * 8);

#pragma unroll
    for (int t = 0; t < 2; ++t) {
      const int Qt = qb + t * 16;
      f32x4 st[2];
#pragma unroll
      for (int u = 0; u < 2; ++u) {
        f32x4 a = {};
        a = __builtin_amdgcn_mfma_f32_16x16x32_bf16(kf[u][0], qf[t][0], a, 0, 0, 0);
        a = __builtin_amdgcn_mfma_f32_16x16x32_bf16(kf[u][1], qf[t][1], a, 0, 0, 0);
        st[u] = a;  // element: q = Qt+lr (col), k = k0+u*16+lg*4+r (row)
      }
      float p[2][4];
      if (k0 + 131 <= Qt) {            // whole step below band: pos = pdr[q][0]
#pragma unroll
        for (int u = 0; u < 2; ++u)
#pragma unroll
          for (int r = 0; r < 4; ++r)
            p[u][r] = fexp2(fmaf(st[u][r], POS_C, pe0[t]));
      } else if (k0 >= Qt + 115) {     // whole step above band: pos = pdr[q][200]
#pragma unroll
        for (int u = 0; u < 2; ++u)
#pragma unroll
          for (int r = 0; r < 4; ++r)
            p[u][r] = fexp2(fmaf(st[u][r], POS_C, pe200[t]));
      } else {                         // in-band: clamped gather (contiguous j)
#pragma unroll
        for (int u = 0; u < 2; ++u) {
          const int jb = k0 + u * 16 + 100 - Qt + ldelta;
#pragma unroll
          for (int r = 0; r < 4; ++r) {
            int j = jb + r;
            j = j < 0 ? 0 : (j > 200 ? 200 : j);
            p[u][r] = fexp2(fmaf(st[u][r], POS_C, b2f(rb[t][j])));
          }
        }
      }
#pragma unroll
      for (int u = 0; u < 2; ++u)
#pragma unroll
        for (int r = 0; r < 4; ++r) psum[t] += p[u][r];
      // pack to bf16, wave-private LDS transpose (D-layout -> B-frag layout)
#pragma unroll
      for (int u = 0; u < 2; ++u) {
        uint2 pk;
        pk.x = pack2(p[u][0], p[u][1]);
        pk.y = pack2(p[u][2], p[u][3]);
        *reinterpret_cast<uint2*>(&Pl[wv][t][lr][u * 8 + lg * 2]) = pk;
      }
    }
    // PV: A = Vt fragment, B = P fragment read back from LDS
    bf16x8 pb[2];
#pragma unroll
    for (int t = 0; t < 2; ++t)
      pb[t] = *reinterpret_cast<const bf16x8*>(&Pl[wv][t][lr][lg * 4]);
#pragma unroll
    for (int f = 0; f < 4; ++f) {
      bf16x8 vf = *reinterpret_cast<const bf16x8*>(Vp + (size_t)(f * 16 + lr) * Lseq + k0 + lg * 8);
#pragma unroll
      for (int t = 0; t < 2; ++t)
        Oacc[t][f] = __builtin_amdgcn_mfma_f32_16x16x32_bf16(vf, pb[t], Oacc[t][f], 0, 0, 0);
    }
  }

  // ---- merge the two k-halves (no-max partials combine by pure addition) ----
  if (kh) {
    float* m = Ml[pair][lane];
#pragma unroll
    for (int t = 0; t < 2; ++t)
#pragma unroll
      for (int f = 0; f < 4; ++f)
#pragma unroll
        for (int r = 0; r < 4; ++r) m[t * 16 + f * 4 + r] = Oacc[t][f][r];
    m[32] = psum[0];
    m[33] = psum[1];
  }
  __syncthreads();
  if (!kh) {
    const float* m = Ml[pair][lane];
#pragma unroll
    for (int t = 0; t < 2; ++t)
#pragma unroll
      for (int f = 0; f < 4; ++f)
#pragma unroll
        for (int r = 0; r < 4; ++r) Oacc[t][f][r] += m[t * 16 + f * 4 + r];
    const int gb = bh >> 3, hh = bh & 7;
#pragma unroll
    for (int t = 0; t < 2; ++t) {
      float s = psum[t] + m[32 + t];
      s += __shfl_xor(s, 16);
      s += __shfl_xor(s, 32);
      const float inv = 1.0f / s;
      const int qg = qb + t * 16 + lr;
#pragma unroll
      for (int f = 0; f < 4; ++f) {
        uint2 ov;
        ov.x = pack2(Oacc[t][f][0] * inv, Oacc[t][f][1] * inv);
        ov.y = pack2(Oacc[t][f][2] * inv, Oacc[t][f][3] * inv);
        *reinterpret_cast<uint2*>(attnb + ((size_t)(gb * Lseq + qg)) * Dm + hh * DKd + f * 16 + lg * 4) = ov;
      }
    }
  }
}

// ---------------- row LayerNorm over D=512 ------------------------------------
__global__ __launch_bounds__(256) void k_ln(const float* __restrict__ y,
                                            const float* __restrict__ g,
                                            const float* __restrict__ be,
                                            float* __restrict__ out) {
  const int row = blockIdx.x * 4 + (threadIdx.x >> 6);
  const int lane = threadIdx.x & 63;
  const float* yp = y + (size_t)row * Dm + lane * 8;
  float4 v0 = *reinterpret_cast<const float4*>(yp);
  float4 v1 = *reinterpret_cast<const float4*>(yp + 4);
  float vv[8] = {v0.x, v0.y, v0.z, v0.w, v1.x, v1.y, v1.z, v1.w};
  float s = 0.f, s2 = 0.f;
#pragma unroll
  for (int j = 0; j < 8; ++j) { s += vv[j]; s2 += vv[j] * vv[j]; }
  for (int mk = 1; mk < 64; mk <<= 1) {
    s += __shfl_xor(s, mk, 64);
    s2 += __shfl_xor(s2, mk, 64);
  }
  const float mu = s * (1.0f / Dm);
  const float var = s2 * (1.0f / Dm) - mu * mu;
  const float inv = rsqrtf(var + 1e-6f);
  float* op = out + (size_t)row * Dm + lane * 8;
  const float* gp = g + lane * 8;
  const float* bp = be + lane * 8;
#pragma unroll
  for (int j = 0; j < 8; ++j) op[j] = (vv[j] - mu) * inv * gp[j] + bp[j];
}

// ------------------------------------------------------------------------------
extern "C" void kernel_launch(void* const* d_in, const int* in_sizes, int n_in,
                              void* d_out, int out_size, void* d_ws, size_t ws_size,
                              hipStream_t stream) {
  const float* q   = (const float*)d_in[0];
  const float* k   = (const float*)d_in[1];
  const float* v   = (const float*)d_in[2];
  const float* Wq  = (const float*)d_in[3];
  const float* Wk  = (const float*)d_in[4];
  const float* Wv  = (const float*)d_in[5];
  const float* Wfc = (const float*)d_in[6];
  const float* rel = (const float*)d_in[7];
  const float* gam = (const float*)d_in[8];
  const float* bet = (const float*)d_in[9];

  char* ws = (char*)d_ws;
  size_t off = 0;
  auto take = [&](size_t bytes) {
    char* p = ws + off;
    off += (bytes + 255) & ~(size_t)255;
    return p;
  };
  bf16_t* wqb  = (bf16_t*)take((size_t)Dm * Dm * 2);
  bf16_t* wkb  = (bf16_t*)take((size_t)Dm * Dm * 2);
  bf16_t* wvb  = (bf16_t*)take((size_t)Dm * Dm * 2);
  bf16_t* wfcb = (bf16_t*)take((size_t)Dm * Dm * 2);
  bf16_t* relb = (bf16_t*)take((size_t)NREL * DKd * 2);
  bf16_t* Qhp  = (bf16_t*)take((size_t)MTOK * Dm * 2);
  bf16_t* Khp  = (bf16_t*)take((size_t)MTOK * Dm * 2);
  bf16_t* Vtp  = (bf16_t*)take((size_t)MTOK * Dm * 2);
  bf16_t* posd = (bf16_t*)take((size_t)Bz * Hh * Lseq * NREL * 2);
  bf16_t* attnb= (bf16_t*)take((size_t)MTOK * Dm * 2);
  float*  yf   = (float*)take((size_t)MTOK * Dm * 4);

  // 1) weights + rel cast (one launch)
  k_castw<<<dim3(Dm * Dm / 1024, 5), 256, 0, stream>>>(
      Wq, Wk, Wv, Wfc, rel, wqb, wkb, wvb, wfcb, relb);
  // 2) fused-cast Q/K/V projections (one launch, z = which)
  k_proj<<<dim3(Dm / 64, MTOK / 64, 3), 256, 0, stream>>>(
      q, k, v, wqb, wkb, wvb, Qhp, Khp, Vtp);
  // 3) position dot table
  k_posdot<<<dim3(13, MTOK / 64), 256, 0, stream>>>(Qhp, relb, posd);
  // 4) attention
  k_attn<<<dim3(1024), 256, 0, stream>>>(Qhp, Khp, Vtp, posd, attnb);
  // 5) output GEMM + residual
  k_fc<<<dim3(Dm / 64, MTOK / 64), 256, 0, stream>>>(attnb, wfcb, yf, q);
  // 6) LayerNorm
  k_ln<<<dim3(MTOK / 4), 256, 0, stream>>>(yf, gam, bet, (float*)d_out);
}

// Round 12
// 275.831 us; speedup vs baseline: 1.8265x; 1.1190x over previous
//
#include <hip/hip_runtime.h>
#include <hip/hip_bf16.h>

typedef __bf16 bf16_t;
typedef __bf16 bf16x8 __attribute__((ext_vector_type(8)));
typedef float f32x4 __attribute__((ext_vector_type(4)));

constexpr int Bz = 8, Lseq = 1024, Dm = 512, Hh = 8, DKd = 64;
constexpr int MTOK = Bz * Lseq;   // 8192 tokens
constexpr int NREL = 201;

// pos pre-scale: 0.125 (1/sqrt(dk)) * log2(e), folded so p = exp2(st*C + pos)
#define POS_C 0.18033688011112042f

__device__ inline float fexp2(float x) {
#if __has_builtin(__builtin_amdgcn_exp2f)
  return __builtin_amdgcn_exp2f(x);
#else
  return exp2f(x);
#endif
}
__device__ inline float b2f(unsigned short u) {
  return __builtin_bit_cast(float, (unsigned)u << 16);
}
__device__ inline unsigned pack2(float a, float b) {
  unsigned short ua = __builtin_bit_cast(unsigned short, (bf16_t)a);
  unsigned short ub = __builtin_bit_cast(unsigned short, (bf16_t)b);
  return (unsigned)ua | ((unsigned)ub << 16);
}

// ---------------- one-launch cast of Wq,Wk,Wv,Wfc + rel ----------------------
__global__ __launch_bounds__(256) void k_castw(
    const float* __restrict__ s0, const float* __restrict__ s1,
    const float* __restrict__ s2, const float* __restrict__ s3,
    const float* __restrict__ s4, bf16_t* __restrict__ d0,
    bf16_t* __restrict__ d1, bf16_t* __restrict__ d2, bf16_t* __restrict__ d3,
    bf16_t* __restrict__ d4) {
  const int y = blockIdx.y;
  const float* s = y == 0 ? s0 : y == 1 ? s1 : y == 2 ? s2 : y == 3 ? s3 : s4;
  bf16_t* d = y == 0 ? d0 : y == 1 ? d1 : y == 2 ? d2 : y == 3 ? d3 : d4;
  const int n = y < 4 ? Dm * Dm : NREL * DKd;
  int i = (blockIdx.x * 256 + threadIdx.x) * 4;
  if (i + 3 < n) {
    float4 v = *reinterpret_cast<const float4*>(s + i);
    d[i + 0] = (bf16_t)v.x;
    d[i + 1] = (bf16_t)v.y;
    d[i + 2] = (bf16_t)v.z;
    d[i + 3] = (bf16_t)v.w;
  } else if (i < n) {
    for (; i < n; ++i) d[i] = (bf16_t)s[i];
  }
}

// ---------------- one-launch cast of q,k,v (4194304 elems each) --------------
__global__ __launch_bounds__(256) void k_castx(
    const float* __restrict__ s0, const float* __restrict__ s1,
    const float* __restrict__ s2, bf16_t* __restrict__ d0,
    bf16_t* __restrict__ d1, bf16_t* __restrict__ d2) {
  const int y = blockIdx.y;
  const float* s = y == 0 ? s0 : y == 1 ? s1 : s2;
  bf16_t* d = y == 0 ? d0 : y == 1 ? d1 : d2;
  const int i = (blockIdx.x * 256 + threadIdx.x) * 4;
  float4 v = *reinterpret_cast<const float4*>(s + i);
  d[i + 0] = (bf16_t)v.x;
  d[i + 1] = (bf16_t)v.y;
  d[i + 2] = (bf16_t)v.z;
  d[i + 3] = (bf16_t)v.w;
}

// ---------------- y = A @ W^T  (A:[8192][512] bf16, W:[512][512] bf16) --------
// XCD-chunked swizzle: each XCD owns 16 contiguous row-blocks x all 8
// col-blocks, so each A row-panel is fetched by exactly one XCD's L2.
// MODE 0: bf16 head-major; MODE 1: bf16 head-transposed; MODE 2: fp32 + resid.
template <int MODE>
__global__ __launch_bounds__(256) void k_gemm512(const bf16_t* __restrict__ A,
                                                 const bf16_t* __restrict__ W,
                                                 bf16_t* __restrict__ outb,
                                                 float* __restrict__ outf,
                                                 const float* __restrict__ resid) {
  const int lane = threadIdx.x & 63, w = threadIdx.x >> 6;
  const int lr = lane & 15, lg = lane >> 4;
  // bijective chunked XCD swizzle (nwg=1024, chunk=128)
  const int orig = blockIdx.x + blockIdx.y * 8;
  const int swz = ((orig & 7) << 7) | (orig >> 3);
  const int Rbase = (swz >> 3) * 64 + (w >> 1) * 32;
  const int Cbase = (swz & 7) * 64 + (w & 1) * 32;

  f32x4 acc[2][2] = {};
  for (int k0 = 0; k0 < Dm; k0 += 32) {
    bf16x8 af[2], wf[2];
#pragma unroll
    for (int i = 0; i < 2; ++i)
      af[i] = *reinterpret_cast<const bf16x8*>(A + (size_t)(Rbase + i * 16 + lr) * Dm + k0 + lg * 8);
#pragma unroll
    for (int j = 0; j < 2; ++j)
      wf[j] = *reinterpret_cast<const bf16x8*>(W + (size_t)(Cbase + j * 16 + lr) * Dm + k0 + lg * 8);
#pragma unroll
    for (int i = 0; i < 2; ++i)
#pragma unroll
      for (int j = 0; j < 2; ++j)
        acc[i][j] = __builtin_amdgcn_mfma_f32_16x16x32_bf16(af[i], wf[j], acc[i][j], 0, 0, 0);
  }
#pragma unroll
  for (int i = 0; i < 2; ++i)
#pragma unroll
    for (int j = 0; j < 2; ++j)
#pragma unroll
      for (int r = 0; r < 4; ++r) {
        const int gr = Rbase + i * 16 + lg * 4 + r;  // token row
        const int gc = Cbase + j * 16 + lr;          // output col
        const float vv = acc[i][j][r];
        if (MODE == 0) {
          const int bb = gr >> 10, qq = gr & 1023, hh = gc >> 6, dd = gc & 63;
          outb[(((size_t)(bb * Hh + hh)) * Lseq + qq) * DKd + dd] = (bf16_t)vv;
        } else if (MODE == 1) {
          const int bb = gr >> 10, qq = gr & 1023, hh = gc >> 6, dd = gc & 63;
          outb[(((size_t)(bb * Hh + hh)) * DKd + dd) * Lseq + qq] = (bf16_t)vv;
        } else {
          const size_t idx = (size_t)gr * Dm + gc;
          outf[idx] = vv + resid[idx];
        }
      }
}

// ---------------- pos_dot, stored REVERSED and PRE-SCALED ---------------------
// pdr[q][j] = POS_C * (Qh[q] . rel_emb[200-j]);  in-band j = k - q + 100.
__global__ __launch_bounds__(256) void k_posdot(const bf16_t* __restrict__ Qh,
                                                const bf16_t* __restrict__ relb,
                                                bf16_t* __restrict__ posd) {
  const int lane = threadIdx.x & 63, w = threadIdx.x >> 6;
  const int lr = lane & 15, lg = lane >> 4;
  // bijective chunked XCD swizzle (nwg=1664, chunk=208)
  const int orig = blockIdx.x + blockIdx.y * 13;
  const int swz = (orig & 7) * 208 + (orig >> 3);
  const int m0 = (swz / 13) * 64 + w * 16;
  const int n0 = (swz % 13) * 16;
  const int r = n0 + lr;

  bf16x8 a0 = *reinterpret_cast<const bf16x8*>(Qh + (size_t)(m0 + lr) * DKd + lg * 8);
  bf16x8 a1 = *reinterpret_cast<const bf16x8*>(Qh + (size_t)(m0 + lr) * DKd + 32 + lg * 8);
  bf16x8 b0 = {}, b1 = {};
  if (r < NREL) {
    b0 = *reinterpret_cast<const bf16x8*>(relb + (size_t)r * DKd + lg * 8);
    b1 = *reinterpret_cast<const bf16x8*>(relb + (size_t)r * DKd + 32 + lg * 8);
  }
  f32x4 acc = {};
  acc = __builtin_amdgcn_mfma_f32_16x16x32_bf16(a0, b0, acc, 0, 0, 0);
  acc = __builtin_amdgcn_mfma_f32_16x16x32_bf16(a1, b1, acc, 0, 0, 0);
#pragma unroll
  for (int rr = 0; rr < 4; ++rr) {
    const int row = m0 + lg * 4 + rr;
    const int col = n0 + lr;
    if (col < NREL)
      posd[(size_t)row * NREL + (200 - col)] = (bf16_t)(acc[rr] * POS_C);
  }
}

// ---------------- flash attention: r7 body, 4-way k-split ---------------------
// Block = 4 waves = 1 (bh, 32-q-tile) unit x 4 k-quarters; grid 2048 blocks
// (8 blocks/CU requested, LDS-limited 6 -> 24 waves/CU vs r7's grid-limited 16).
// Per-wave register structure IDENTICAL to r7 (117us, no spill): no prefetch,
// no VGPR cap, kf loaded per step. LDS: Pl (10.2KB) union Ml (26.1KB).
__global__ __launch_bounds__(256, 4) void k_attn(const bf16_t* __restrict__ Qh,
                                                 const bf16_t* __restrict__ Kh,
                                                 const bf16_t* __restrict__ Vt,
                                                 const bf16_t* __restrict__ posd,
                                                 bf16_t* __restrict__ attnb) {
  __shared__ float smemf[6528];   // max(Pl 10240B, Ml 26112B)

  const int tid = threadIdx.x;
  const int wv = tid >> 6, lane = tid & 63;
  const int lr = lane & 15, lg = lane >> 4;
  // bijective chunked XCD swizzle (nwg=2048, chunk=256)
  const int gid = ((blockIdx.x & 7) << 8) | (blockIdx.x >> 3);
  const int bh = gid >> 5;
  const int qb = (gid & 31) << 5;             // 32-row q tile

  unsigned* Pw = reinterpret_cast<unsigned*>(smemf) + wv * 640;  // [2][16][20]

  const bf16_t* Qp = Qh + ((size_t)bh * Lseq + qb) * DKd;
  const bf16_t* Kp = Kh + (size_t)bh * Lseq * DKd;
  const bf16_t* Vp = Vt + (size_t)bh * DKd * Lseq;
  const unsigned short* pu =
      (const unsigned short*)posd + ((size_t)bh * Lseq + qb) * NREL;

  // per-lane pos row bases + band-edge constants (already scaled by POS_C)
  const unsigned short* rb[2] = {pu + (size_t)lr * NREL,
                                 pu + (size_t)(16 + lr) * NREL};
  float pe0[2], pe200[2];
#pragma unroll
  for (int t = 0; t < 2; ++t) {
    pe0[t] = b2f(rb[t][0]);       // k <= q-100 side
    pe200[t] = b2f(rb[t][200]);   // k >= q+100 side
  }

  // Q fragments (B-operand: lane&15 = q col, lg*8 = d dims, h = d-half)
  bf16x8 qf[2][2];
#pragma unroll
  for (int t = 0; t < 2; ++t)
#pragma unroll
    for (int h = 0; h < 2; ++h)
      qf[t][h] = *reinterpret_cast<const bf16x8*>(Qp + (size_t)(t * 16 + lr) * DKd + h * 32 + lg * 8);

  f32x4 Oacc[2][4] = {};
  float psum[2] = {0.f, 0.f};
  const int ldelta = lg * 4 - lr;

  const int kbase = wv * 256;
#pragma unroll 2
  for (int k0 = kbase; k0 < kbase + 256; k0 += 32) {
    // K fragments (A-operand: lane&15 = k row, lg*8 = d dims)
    bf16x8 kf[2][2];
#pragma unroll
    for (int u = 0; u < 2; ++u)
#pragma unroll
      for (int h = 0; h < 2; ++h)
        kf[u][h] = *reinterpret_cast<const bf16x8*>(Kp + (size_t)(k0 + u * 16 + lr) * DKd + h * 32 + lg * 8);

#pragma unroll
    for (int t = 0; t < 2; ++t) {
      const int Qt = qb + t * 16;
      f32x4 st[2];
#pragma unroll
      for (int u = 0; u < 2; ++u) {
        f32x4 a = {};
        a = __builtin_amdgcn_mfma_f32_16x16x32_bf16(kf[u][0], qf[t][0], a, 0, 0, 0);
        a = __builtin_amdgcn_mfma_f32_16x16x32_bf16(kf[u][1], qf[t][1], a, 0, 0, 0);
        st[u] = a;  // element: q = Qt+lr (col), k = k0+u*16+lg*4+r (row)
      }
      float p[2][4];
      if (k0 + 131 <= Qt) {            // whole step below band: pos = pdr[q][0]
#pragma unroll
        for (int u = 0; u < 2; ++u)
#pragma unroll
          for (int r = 0; r < 4; ++r)
            p[u][r] = fexp2(fmaf(st[u][r], POS_C, pe0[t]));
      } else if (k0 >= Qt + 115) {     // whole step above band: pos = pdr[q][200]
#pragma unroll
        for (int u = 0; u < 2; ++u)
#pragma unroll
          for (int r = 0; r < 4; ++r)
            p[u][r] = fexp2(fmaf(st[u][r], POS_C, pe200[t]));
      } else {                         // in-band: clamped gather (contiguous j)
#pragma unroll
        for (int u = 0; u < 2; ++u) {
          const int jb = k0 + u * 16 + 100 - Qt + ldelta;
#pragma unroll
          for (int r = 0; r < 4; ++r) {
            int j = jb + r;
            j = j < 0 ? 0 : (j > 200 ? 200 : j);
            p[u][r] = fexp2(fmaf(st[u][r], POS_C, b2f(rb[t][j])));
          }
        }
      }
#pragma unroll
      for (int u = 0; u < 2; ++u)
#pragma unroll
        for (int r = 0; r < 4; ++r) psum[t] += p[u][r];
      // pack to bf16, wave-private LDS transpose (D-layout -> B-frag layout)
#pragma unroll
      for (int u = 0; u < 2; ++u) {
        uint2 pk;
        pk.x = pack2(p[u][0], p[u][1]);
        pk.y = pack2(p[u][2], p[u][3]);
        *reinterpret_cast<uint2*>(&Pw[t * 320 + lr * 20 + u * 8 + lg * 2]) = pk;
      }
    }
    // PV: A = Vt fragment, B = P fragment read back from LDS
    bf16x8 pb[2];
#pragma unroll
    for (int t = 0; t < 2; ++t)
      pb[t] = *reinterpret_cast<const bf16x8*>(&Pw[t * 320 + lr * 20 + lg * 4]);
#pragma unroll
    for (int f = 0; f < 4; ++f) {
      bf16x8 vf = *reinterpret_cast<const bf16x8*>(Vp + (size_t)(f * 16 + lr) * Lseq + k0 + lg * 8);
#pragma unroll
      for (int t = 0; t < 2; ++t)
        Oacc[t][f] = __builtin_amdgcn_mfma_f32_16x16x32_bf16(vf, pb[t], Oacc[t][f], 0, 0, 0);
    }
  }

  // ---- merge the four k-quarters (no-max partials combine by pure addition) --
  __syncthreads();   // all k-loops done; Pl region dead -> reuse as Ml[3][64][34]
  float* Ml = smemf;
  if (wv) {
    float* m = Ml + ((wv - 1) * 64 + lane) * 34;
#pragma unroll
    for (int t = 0; t < 2; ++t)
#pragma unroll
      for (int f = 0; f < 4; ++f)
#pragma unroll
        for (int r = 0; r < 4; ++r) m[t * 16 + f * 4 + r] = Oacc[t][f][r];
    m[32] = psum[0];
    m[33] = psum[1];
  }
  __syncthreads();
  if (!wv) {
#pragma unroll
    for (int w2 = 0; w2 < 3; ++w2) {
      const float* m = Ml + (w2 * 64 + lane) * 34;
#pragma unroll
      for (int t = 0; t < 2; ++t) {
#pragma unroll
        for (int f = 0; f < 4; ++f)
#pragma unroll
          for (int r = 0; r < 4; ++r) Oacc[t][f][r] += m[t * 16 + f * 4 + r];
        psum[t] += m[32 + t];
      }
    }
    const int gb = bh >> 3, hh = bh & 7;
#pragma unroll
    for (int t = 0; t < 2; ++t) {
      float s = psum[t];
      s += __shfl_xor(s, 16);
      s += __shfl_xor(s, 32);
      const float inv = 1.0f / s;
      const int qg = qb + t * 16 + lr;
#pragma unroll
      for (int f = 0; f < 4; ++f) {
        uint2 ov;
        ov.x = pack2(Oacc[t][f][0] * inv, Oacc[t][f][1] * inv);
        ov.y = pack2(Oacc[t][f][2] * inv, Oacc[t][f][3] * inv);
        *reinterpret_cast<uint2*>(attnb + ((size_t)(gb * Lseq + qg)) * Dm + hh * DKd + f * 16 + lg * 4) = ov;
      }
    }
  }
}

// ---------------- row LayerNorm over D=512 ------------------------------------
__global__ __launch_bounds__(256) void k_ln(const float* __restrict__ y,
                                            const float* __restrict__ g,
                                            const float* __restrict__ be,
                                            float* __restrict__ out) {
  const int row = blockIdx.x * 4 + (threadIdx.x >> 6);
  const int lane = threadIdx.x & 63;
  const float* yp = y + (size_t)row * Dm + lane * 8;
  float4 v0 = *reinterpret_cast<const float4*>(yp);
  float4 v1 = *reinterpret_cast<const float4*>(yp + 4);
  float vv[8] = {v0.x, v0.y, v0.z, v0.w, v1.x, v1.y, v1.z, v1.w};
  float s = 0.f, s2 = 0.f;
#pragma unroll
  for (int j = 0; j < 8; ++j) { s += vv[j]; s2 += vv[j] * vv[j]; }
  for (int mk = 1; mk < 64; mk <<= 1) {
    s += __shfl_xor(s, mk, 64);
    s2 += __shfl_xor(s2, mk, 64);
  }
  const float mu = s * (1.0f / Dm);
  const float var = s2 * (1.0f / Dm) - mu * mu;
  const float inv = rsqrtf(var + 1e-6f);
  float* op = out + (size_t)row * Dm + lane * 8;
  const float* gp = g + lane * 8;
  const float* bp = be + lane * 8;
#pragma unroll
  for (int j = 0; j < 8; ++j) op[j] = (vv[j] - mu) * inv * gp[j] + bp[j];
}

// ------------------------------------------------------------------------------
extern "C" void kernel_launch(void* const* d_in, const int* in_sizes, int n_in,
                              void* d_out, int out_size, void* d_ws, size_t ws_size,
                              hipStream_t stream) {
  const float* q   = (const float*)d_in[0];
  const float* k   = (const float*)d_in[1];
  const float* v   = (const float*)d_in[2];
  const float* Wq  = (const float*)d_in[3];
  const float* Wk  = (const float*)d_in[4];
  const float* Wv  = (const float*)d_in[5];
  const float* Wfc = (const float*)d_in[6];
  const float* rel = (const float*)d_in[7];
  const float* gam = (const float*)d_in[8];
  const float* bet = (const float*)d_in[9];

  char* ws = (char*)d_ws;
  size_t off = 0;
  auto take = [&](size_t bytes) {
    char* p = ws + off;
    off += (bytes + 255) & ~(size_t)255;
    return p;
  };
  bf16_t* wqb  = (bf16_t*)take((size_t)Dm * Dm * 2);
  bf16_t* wkb  = (bf16_t*)take((size_t)Dm * Dm * 2);
  bf16_t* wvb  = (bf16_t*)take((size_t)Dm * Dm * 2);
  bf16_t* wfcb = (bf16_t*)take((size_t)Dm * Dm * 2);
  bf16_t* relb = (bf16_t*)take((size_t)NREL * DKd * 2);
  bf16_t* qb   = (bf16_t*)take((size_t)MTOK * Dm * 2);
  bf16_t* kb   = (bf16_t*)take((size_t)MTOK * Dm * 2);
  bf16_t* vb   = (bf16_t*)take((size_t)MTOK * Dm * 2);
  bf16_t* Qhp  = (bf16_t*)take((size_t)MTOK * Dm * 2);
  bf16_t* Khp  = (bf16_t*)take((size_t)MTOK * Dm * 2);
  bf16_t* Vtp  = (bf16_t*)take((size_t)MTOK * Dm * 2);
  bf16_t* posd = (bf16_t*)take((size_t)Bz * Hh * Lseq * NREL * 2);
  bf16_t* attnb= (bf16_t*)take((size_t)MTOK * Dm * 2);
  float*  yf   = (float*)take((size_t)MTOK * Dm * 4);

  // 1) weights + rel cast (one launch)
  k_castw<<<dim3(Dm * Dm / 1024, 5), 256, 0, stream>>>(
      Wq, Wk, Wv, Wfc, rel, wqb, wkb, wvb, wfcb, relb);
  // 2) q/k/v cast (one launch)
  k_castx<<<dim3(MTOK * Dm / 1024, 3), 256, 0, stream>>>(
      q, k, v, qb, kb, vb);
  // 3) projections (bf16 A path, proven in r7)
  dim3 gg(Dm / 64, MTOK / 64);
  k_gemm512<0><<<gg, 256, 0, stream>>>(qb, wqb, Qhp, nullptr, nullptr);
  k_gemm512<0><<<gg, 256, 0, stream>>>(kb, wkb, Khp, nullptr, nullptr);
  k_gemm512<1><<<gg, 256, 0, stream>>>(vb, wvb, Vtp, nullptr, nullptr);
  // 4) position dot table
  k_posdot<<<dim3(13, MTOK / 64), 256, 0, stream>>>(Qhp, relb, posd);
  // 5) attention (4-way k-split, r7 body)
  k_attn<<<dim3(2048), 256, 0, stream>>>(Qhp, Khp, Vtp, posd, attnb);
  // 6) output GEMM + residual
  k_gemm512<2><<<gg, 256, 0, stream>>>(attnb, wfcb, nullptr, yf, q);
  // 7) LayerNorm
  k_ln<<<dim3(MTOK / 4), 256, 0, stream>>>(yf, gam, bet, (float*)d_out);
}

// Round 13
// 235.179 us; speedup vs baseline: 2.1422x; 1.1729x over previous
//
#include <hip/hip_runtime.h>
#include <hip/hip_bf16.h>

typedef __bf16 bf16_t;
typedef __bf16 bf16x8 __attribute__((ext_vector_type(8)));
typedef float f32x4 __attribute__((ext_vector_type(4)));

constexpr int Bz = 8, Lseq = 1024, Dm = 512, Hh = 8, DKd = 64;
constexpr int MTOK = Bz * Lseq;   // 8192 tokens
constexpr int NREL = 201;
constexpr int PROW = 202;         // padded LDS row (bank stride 101%32=5, coprime)

// pos pre-scale: 0.125 (1/sqrt(dk)) * log2(e), folded so p = exp2(st*C + pos)
#define POS_C 0.18033688011112042f

__device__ inline float fexp2(float x) {
#if __has_builtin(__builtin_amdgcn_exp2f)
  return __builtin_amdgcn_exp2f(x);
#else
  return exp2f(x);
#endif
}
__device__ inline float b2f(unsigned short u) {
  return __builtin_bit_cast(float, (unsigned)u << 16);
}
__device__ inline unsigned pack2(float a, float b) {
  unsigned short ua = __builtin_bit_cast(unsigned short, (bf16_t)a);
  unsigned short ub = __builtin_bit_cast(unsigned short, (bf16_t)b);
  return (unsigned)ua | ((unsigned)ub << 16);
}

// ---------------- one-launch cast of Wq,Wk,Wv,Wfc + rel ----------------------
__global__ __launch_bounds__(256) void k_castw(
    const float* __restrict__ s0, const float* __restrict__ s1,
    const float* __restrict__ s2, const float* __restrict__ s3,
    const float* __restrict__ s4, bf16_t* __restrict__ d0,
    bf16_t* __restrict__ d1, bf16_t* __restrict__ d2, bf16_t* __restrict__ d3,
    bf16_t* __restrict__ d4) {
  const int y = blockIdx.y;
  const float* s = y == 0 ? s0 : y == 1 ? s1 : y == 2 ? s2 : y == 3 ? s3 : s4;
  bf16_t* d = y == 0 ? d0 : y == 1 ? d1 : y == 2 ? d2 : y == 3 ? d3 : d4;
  const int n = y < 4 ? Dm * Dm : NREL * DKd;
  int i = (blockIdx.x * 256 + threadIdx.x) * 4;
  if (i + 3 < n) {
    float4 v = *reinterpret_cast<const float4*>(s + i);
    d[i + 0] = (bf16_t)v.x;
    d[i + 1] = (bf16_t)v.y;
    d[i + 2] = (bf16_t)v.z;
    d[i + 3] = (bf16_t)v.w;
  } else if (i < n) {
    for (; i < n; ++i) d[i] = (bf16_t)s[i];
  }
}

// ---------------- one-launch cast of q,k,v (4194304 elems each) --------------
__global__ __launch_bounds__(256) void k_castx(
    const float* __restrict__ s0, const float* __restrict__ s1,
    const float* __restrict__ s2, bf16_t* __restrict__ d0,
    bf16_t* __restrict__ d1, bf16_t* __restrict__ d2) {
  const int y = blockIdx.y;
  const float* s = y == 0 ? s0 : y == 1 ? s1 : s2;
  bf16_t* d = y == 0 ? d0 : y == 1 ? d1 : d2;
  const int i = (blockIdx.x * 256 + threadIdx.x) * 4;
  float4 v = *reinterpret_cast<const float4*>(s + i);
  d[i + 0] = (bf16_t)v.x;
  d[i + 1] = (bf16_t)v.y;
  d[i + 2] = (bf16_t)v.z;
  d[i + 3] = (bf16_t)v.w;
}

// ---------------- y = A @ W^T  (A:[8192][512] bf16, W:[512][512] bf16) --------
// MODE 0: bf16 head-major; MODE 1: bf16 head-transposed; MODE 2: fp32 + resid.
template <int MODE>
__global__ __launch_bounds__(256) void k_gemm512(const bf16_t* __restrict__ A,
                                                 const bf16_t* __restrict__ W,
                                                 bf16_t* __restrict__ outb,
                                                 float* __restrict__ outf,
                                                 const float* __restrict__ resid) {
  const int lane = threadIdx.x & 63, w = threadIdx.x >> 6;
  const int lr = lane & 15, lg = lane >> 4;
  // bijective chunked XCD swizzle (nwg=1024, chunk=128)
  const int orig = blockIdx.x + blockIdx.y * 8;
  const int swz = ((orig & 7) << 7) | (orig >> 3);
  const int Rbase = (swz >> 3) * 64 + (w >> 1) * 32;
  const int Cbase = (swz & 7) * 64 + (w & 1) * 32;

  f32x4 acc[2][2] = {};
  for (int k0 = 0; k0 < Dm; k0 += 32) {
    bf16x8 af[2], wf[2];
#pragma unroll
    for (int i = 0; i < 2; ++i)
      af[i] = *reinterpret_cast<const bf16x8*>(A + (size_t)(Rbase + i * 16 + lr) * Dm + k0 + lg * 8);
#pragma unroll
    for (int j = 0; j < 2; ++j)
      wf[j] = *reinterpret_cast<const bf16x8*>(W + (size_t)(Cbase + j * 16 + lr) * Dm + k0 + lg * 8);
#pragma unroll
    for (int i = 0; i < 2; ++i)
#pragma unroll
      for (int j = 0; j < 2; ++j)
        acc[i][j] = __builtin_amdgcn_mfma_f32_16x16x32_bf16(af[i], wf[j], acc[i][j], 0, 0, 0);
  }
#pragma unroll
  for (int i = 0; i < 2; ++i)
#pragma unroll
    for (int j = 0; j < 2; ++j)
#pragma unroll
      for (int r = 0; r < 4; ++r) {
        const int gr = Rbase + i * 16 + lg * 4 + r;  // token row
        const int gc = Cbase + j * 16 + lr;          // output col
        const float vv = acc[i][j][r];
        if (MODE == 0) {
          const int bb = gr >> 10, qq = gr & 1023, hh = gc >> 6, dd = gc & 63;
          outb[(((size_t)(bb * Hh + hh)) * Lseq + qq) * DKd + dd] = (bf16_t)vv;
        } else if (MODE == 1) {
          const int bb = gr >> 10, qq = gr & 1023, hh = gc >> 6, dd = gc & 63;
          outb[(((size_t)(bb * Hh + hh)) * DKd + dd) * Lseq + qq] = (bf16_t)vv;
        } else {
          const size_t idx = (size_t)gr * Dm + gc;
          outf[idx] = vv + resid[idx];
        }
      }
}

// ---------------- pos_dot, stored REVERSED and PRE-SCALED ---------------------
// pdr[q][j] = POS_C * (Qh[q] . rel_emb[200-j]);  in-band j = k - q + 100.
__global__ __launch_bounds__(256) void k_posdot(const bf16_t* __restrict__ Qh,
                                                const bf16_t* __restrict__ relb,
                                                bf16_t* __restrict__ posd) {
  const int lane = threadIdx.x & 63, w = threadIdx.x >> 6;
  const int lr = lane & 15, lg = lane >> 4;
  // bijective chunked XCD swizzle (nwg=1664, chunk=208)
  const int orig = blockIdx.x + blockIdx.y * 13;
  const int swz = (orig & 7) * 208 + (orig >> 3);
  const int m0 = (swz / 13) * 64 + w * 16;
  const int n0 = (swz % 13) * 16;
  const int r = n0 + lr;

  bf16x8 a0 = *reinterpret_cast<const bf16x8*>(Qh + (size_t)(m0 + lr) * DKd + lg * 8);
  bf16x8 a1 = *reinterpret_cast<const bf16x8*>(Qh + (size_t)(m0 + lr) * DKd + 32 + lg * 8);
  bf16x8 b0 = {}, b1 = {};
  if (r < NREL) {
    b0 = *reinterpret_cast<const bf16x8*>(relb + (size_t)r * DKd + lg * 8);
    b1 = *reinterpret_cast<const bf16x8*>(relb + (size_t)r * DKd + 32 + lg * 8);
  }
  f32x4 acc = {};
  acc = __builtin_amdgcn_mfma_f32_16x16x32_bf16(a0, b0, acc, 0, 0, 0);
  acc = __builtin_amdgcn_mfma_f32_16x16x32_bf16(a1, b1, acc, 0, 0, 0);
#pragma unroll
  for (int rr = 0; rr < 4; ++rr) {
    const int row = m0 + lg * 4 + rr;
    const int col = n0 + lr;
    if (col < NREL)
      posd[(size_t)row * NREL + (200 - col)] = (bf16_t)(acc[rr] * POS_C);
  }
}

// ---------------- flash attention: 4-way k-split + LDS-staged pos table -------
// The in-band pos gathers previously hit GLOBAL memory with 402B lane stride:
// ~64 L2 lines per instruction, 32x over-fetch -> L2-BW-bound (hidden from HBM
// counters by L2 residency). Now the unit's 32 posd rows (12.9KB) are staged
// into LDS once per block (coalesced) and gathered via ds_read_u16 from a
// +1-padded layout (bank stride 101%32=5 -> ~2-way, free).
__global__ __launch_bounds__(256, 4) void k_attn(const bf16_t* __restrict__ Qh,
                                                 const bf16_t* __restrict__ Kh,
                                                 const bf16_t* __restrict__ Vt,
                                                 const bf16_t* __restrict__ posd,
                                                 bf16_t* __restrict__ attnb) {
  __shared__ float smemf[6528];   // pos 12928B + Pl 10240B = 23168B; Ml 26112B

  const int tid = threadIdx.x;
  const int wv = tid >> 6, lane = tid & 63;
  const int lr = lane & 15, lg = lane >> 4;
  // bijective chunked XCD swizzle (nwg=2048, chunk=256)
  const int gid = ((blockIdx.x & 7) << 8) | (blockIdx.x >> 3);
  const int bh = gid >> 5;
  const int qb = (gid & 31) << 5;             // 32-row q tile

  unsigned short* pls = reinterpret_cast<unsigned short*>(smemf);     // [32][202]
  unsigned* Pw = reinterpret_cast<unsigned*>(smemf) + 3232 + wv * 640; // [2][16][20]

  const bf16_t* Qp = Qh + ((size_t)bh * Lseq + qb) * DKd;
  const bf16_t* Kp = Kh + (size_t)bh * Lseq * DKd;
  const bf16_t* Vp = Vt + (size_t)bh * DKd * Lseq;
  const unsigned short* pu =
      (const unsigned short*)posd + ((size_t)bh * Lseq + qb) * NREL;

  // cooperative coalesced stage of the 32 pos rows into padded LDS
  for (int i = tid; i < 32 * NREL; i += 256)
    pls[(i / NREL) * PROW + (i % NREL)] = pu[i];
  __syncthreads();

  // per-lane pos row bases + band-edge constants (already scaled by POS_C)
  const unsigned short* prow[2] = {pls + (size_t)lr * PROW,
                                   pls + (size_t)(16 + lr) * PROW};
  float pe0[2], pe200[2];
#pragma unroll
  for (int t = 0; t < 2; ++t) {
    pe0[t] = b2f(prow[t][0]);       // k <= q-100 side
    pe200[t] = b2f(prow[t][200]);   // k >= q+100 side
  }

  // Q fragments (B-operand: lane&15 = q col, lg*8 = d dims, h = d-half)
  bf16x8 qf[2][2];
#pragma unroll
  for (int t = 0; t < 2; ++t)
#pragma unroll
    for (int h = 0; h < 2; ++h)
      qf[t][h] = *reinterpret_cast<const bf16x8*>(Qp + (size_t)(t * 16 + lr) * DKd + h * 32 + lg * 8);

  f32x4 Oacc[2][4] = {};
  float psum[2] = {0.f, 0.f};
  const int ldelta = lg * 4 - lr;

  const int kbase = wv * 256;
#pragma unroll 2
  for (int k0 = kbase; k0 < kbase + 256; k0 += 32) {
    // K fragments (A-operand: lane&15 = k row, lg*8 = d dims)
    bf16x8 kf[2][2];
#pragma unroll
    for (int u = 0; u < 2; ++u)
#pragma unroll
      for (int h = 0; h < 2; ++h)
        kf[u][h] = *reinterpret_cast<const bf16x8*>(Kp + (size_t)(k0 + u * 16 + lr) * DKd + h * 32 + lg * 8);

#pragma unroll
    for (int t = 0; t < 2; ++t) {
      const int Qt = qb + t * 16;
      f32x4 st[2];
#pragma unroll
      for (int u = 0; u < 2; ++u) {
        f32x4 a = {};
        a = __builtin_amdgcn_mfma_f32_16x16x32_bf16(kf[u][0], qf[t][0], a, 0, 0, 0);
        a = __builtin_amdgcn_mfma_f32_16x16x32_bf16(kf[u][1], qf[t][1], a, 0, 0, 0);
        st[u] = a;  // element: q = Qt+lr (col), k = k0+u*16+lg*4+r (row)
      }
      float p[2][4];
      if (k0 + 131 <= Qt) {            // whole step below band: pos = pdr[q][0]
#pragma unroll
        for (int u = 0; u < 2; ++u)
#pragma unroll
          for (int r = 0; r < 4; ++r)
            p[u][r] = fexp2(fmaf(st[u][r], POS_C, pe0[t]));
      } else if (k0 >= Qt + 115) {     // whole step above band: pos = pdr[q][200]
#pragma unroll
        for (int u = 0; u < 2; ++u)
#pragma unroll
          for (int r = 0; r < 4; ++r)
            p[u][r] = fexp2(fmaf(st[u][r], POS_C, pe200[t]));
      } else {                         // in-band: clamped gather from LDS
#pragma unroll
        for (int u = 0; u < 2; ++u) {
          const int jb = k0 + u * 16 + 100 - Qt + ldelta;
#pragma unroll
          for (int r = 0; r < 4; ++r) {
            int j = jb + r;
            j = j < 0 ? 0 : (j > 200 ? 200 : j);
            p[u][r] = fexp2(fmaf(st[u][r], POS_C, b2f(prow[t][j])));
          }
        }
      }
#pragma unroll
      for (int u = 0; u < 2; ++u)
#pragma unroll
        for (int r = 0; r < 4; ++r) psum[t] += p[u][r];
      // pack to bf16, wave-private LDS transpose (D-layout -> B-frag layout)
#pragma unroll
      for (int u = 0; u < 2; ++u) {
        uint2 pk;
        pk.x = pack2(p[u][0], p[u][1]);
        pk.y = pack2(p[u][2], p[u][3]);
        *reinterpret_cast<uint2*>(&Pw[t * 320 + lr * 20 + u * 8 + lg * 2]) = pk;
      }
    }
    // PV: A = Vt fragment, B = P fragment read back from LDS
    bf16x8 pb[2];
#pragma unroll
    for (int t = 0; t < 2; ++t)
      pb[t] = *reinterpret_cast<const bf16x8*>(&Pw[t * 320 + lr * 20 + lg * 4]);
#pragma unroll
    for (int f = 0; f < 4; ++f) {
      bf16x8 vf = *reinterpret_cast<const bf16x8*>(Vp + (size_t)(f * 16 + lr) * Lseq + k0 + lg * 8);
#pragma unroll
      for (int t = 0; t < 2; ++t)
        Oacc[t][f] = __builtin_amdgcn_mfma_f32_16x16x32_bf16(vf, pb[t], Oacc[t][f], 0, 0, 0);
    }
  }

  // ---- merge the four k-quarters (no-max partials combine by pure addition) --
  __syncthreads();   // k-loops done; pos+Pl dead -> reuse smem as Ml[3][64][34]
  float* Ml = smemf;
  if (wv) {
    float* m = Ml + ((wv - 1) * 64 + lane) * 34;
#pragma unroll
    for (int t = 0; t < 2; ++t)
#pragma unroll
      for (int f = 0; f < 4; ++f)
#pragma unroll
        for (int r = 0; r < 4; ++r) m[t * 16 + f * 4 + r] = Oacc[t][f][r];
    m[32] = psum[0];
    m[33] = psum[1];
  }
  __syncthreads();
  if (!wv) {
#pragma unroll
    for (int w2 = 0; w2 < 3; ++w2) {
      const float* m = Ml + (w2 * 64 + lane) * 34;
#pragma unroll
      for (int t = 0; t < 2; ++t) {
#pragma unroll
        for (int f = 0; f < 4; ++f)
#pragma unroll
          for (int r = 0; r < 4; ++r) Oacc[t][f][r] += m[t * 16 + f * 4 + r];
        psum[t] += m[32 + t];
      }
    }
    const int gb = bh >> 3, hh = bh & 7;
#pragma unroll
    for (int t = 0; t < 2; ++t) {
      float s = psum[t];
      s += __shfl_xor(s, 16);
      s += __shfl_xor(s, 32);
      const float inv = 1.0f / s;
      const int qg = qb + t * 16 + lr;
#pragma unroll
      for (int f = 0; f < 4; ++f) {
        uint2 ov;
        ov.x = pack2(Oacc[t][f][0] * inv, Oacc[t][f][1] * inv);
        ov.y = pack2(Oacc[t][f][2] * inv, Oacc[t][f][3] * inv);
        *reinterpret_cast<uint2*>(attnb + ((size_t)(gb * Lseq + qg)) * Dm + hh * DKd + f * 16 + lg * 4) = ov;
      }
    }
  }
}

// ---------------- row LayerNorm over D=512 ------------------------------------
__global__ __launch_bounds__(256) void k_ln(const float* __restrict__ y,
                                            const float* __restrict__ g,
                                            const float* __restrict__ be,
                                            float* __restrict__ out) {
  const int row = blockIdx.x * 4 + (threadIdx.x >> 6);
  const int lane = threadIdx.x & 63;
  const float* yp = y + (size_t)row * Dm + lane * 8;
  float4 v0 = *reinterpret_cast<const float4*>(yp);
  float4 v1 = *reinterpret_cast<const float4*>(yp + 4);
  float vv[8] = {v0.x, v0.y, v0.z, v0.w, v1.x, v1.y, v1.z, v1.w};
  float s = 0.f, s2 = 0.f;
#pragma unroll
  for (int j = 0; j < 8; ++j) { s += vv[j]; s2 += vv[j] * vv[j]; }
  for (int mk = 1; mk < 64; mk <<= 1) {
    s += __shfl_xor(s, mk, 64);
    s2 += __shfl_xor(s2, mk, 64);
  }
  const float mu = s * (1.0f / Dm);
  const float var = s2 * (1.0f / Dm) - mu * mu;
  const float inv = rsqrtf(var + 1e-6f);
  float* op = out + (size_t)row * Dm + lane * 8;
  const float* gp = g + lane * 8;
  const float* bp = be + lane * 8;
#pragma unroll
  for (int j = 0; j < 8; ++j) op[j] = (vv[j] - mu) * inv * gp[j] + bp[j];
}

// ------------------------------------------------------------------------------
extern "C" void kernel_launch(void* const* d_in, const int* in_sizes, int n_in,
                              void* d_out, int out_size, void* d_ws, size_t ws_size,
                              hipStream_t stream) {
  const float* q   = (const float*)d_in[0];
  const float* k   = (const float*)d_in[1];
  const float* v   = (const float*)d_in[2];
  const float* Wq  = (const float*)d_in[3];
  const float* Wk  = (const float*)d_in[4];
  const float* Wv  = (const float*)d_in[5];
  const float* Wfc = (const float*)d_in[6];
  const float* rel = (const float*)d_in[7];
  const float* gam = (const float*)d_in[8];
  const float* bet = (const float*)d_in[9];

  char* ws = (char*)d_ws;
  size_t off = 0;
  auto take = [&](size_t bytes) {
    char* p = ws + off;
    off += (bytes + 255) & ~(size_t)255;
    return p;
  };
  bf16_t* wqb  = (bf16_t*)take((size_t)Dm * Dm * 2);
  bf16_t* wkb  = (bf16_t*)take((size_t)Dm * Dm * 2);
  bf16_t* wvb  = (bf16_t*)take((size_t)Dm * Dm * 2);
  bf16_t* wfcb = (bf16_t*)take((size_t)Dm * Dm * 2);
  bf16_t* relb = (bf16_t*)take((size_t)NREL * DKd * 2);
  bf16_t* qb   = (bf16_t*)take((size_t)MTOK * Dm * 2);
  bf16_t* kb   = (bf16_t*)take((size_t)MTOK * Dm * 2);
  bf16_t* vb   = (bf16_t*)take((size_t)MTOK * Dm * 2);
  bf16_t* Qhp  = (bf16_t*)take((size_t)MTOK * Dm * 2);
  bf16_t* Khp  = (bf16_t*)take((size_t)MTOK * Dm * 2);
  bf16_t* Vtp  = (bf16_t*)take((size_t)MTOK * Dm * 2);
  bf16_t* posd = (bf16_t*)take((size_t)Bz * Hh * Lseq * NREL * 2);
  bf16_t* attnb= (bf16_t*)take((size_t)MTOK * Dm * 2);
  float*  yf   = (float*)take((size_t)MTOK * Dm * 4);

  // 1) weights + rel cast (one launch)
  k_castw<<<dim3(Dm * Dm / 1024, 5), 256, 0, stream>>>(
      Wq, Wk, Wv, Wfc, rel, wqb, wkb, wvb, wfcb, relb);
  // 2) q/k/v cast (one launch)
  k_castx<<<dim3(MTOK * Dm / 1024, 3), 256, 0, stream>>>(
      q, k, v, qb, kb, vb);
  // 3) projections
  dim3 gg(Dm / 64, MTOK / 64);
  k_gemm512<0><<<gg, 256, 0, stream>>>(qb, wqb, Qhp, nullptr, nullptr);
  k_gemm512<0><<<gg, 256, 0, stream>>>(kb, wkb, Khp, nullptr, nullptr);
  k_gemm512<1><<<gg, 256, 0, stream>>>(vb, wvb, Vtp, nullptr, nullptr);
  // 4) position dot table
  k_posdot<<<dim3(13, MTOK / 64), 256, 0, stream>>>(Qhp, relb, posd);
  // 5) attention (4-way k-split, LDS-staged pos)
  k_attn<<<dim3(2048), 256, 0, stream>>>(Qhp, Khp, Vtp, posd, attnb);
  // 6) output GEMM + residual
  k_gemm512<2><<<gg, 256, 0, stream>>>(attnb, wfcb, nullptr, yf, q);
  // 7) LayerNorm
  k_ln<<<dim3(MTOK / 4), 256, 0, stream>>>(yf, gam, bet, (float*)d_out);
}

// Round 15
// 234.711 us; speedup vs baseline: 2.1465x; 1.0020x over previous
//
#include <hip/hip_runtime.h>
#include <hip/hip_bf16.h>

typedef __bf16 bf16_t;
typedef __bf16 bf16x8 __attribute__((ext_vector_type(8)));
typedef float f32x4 __attribute__((ext_vector_type(4)));

constexpr int Bz = 8, Lseq = 1024, Dm = 512, Hh = 8, DKd = 64;
constexpr int MTOK = Bz * Lseq;   // 8192 tokens
constexpr int NREL = 201;
constexpr int PROW = 202;         // padded LDS row (bank stride 101%32=5, coprime)

// pos pre-scale: 0.125 (1/sqrt(dk)) * log2(e), folded so p = exp2(st*C + pos)
#define POS_C 0.18033688011112042f

__device__ inline float fexp2(float x) {
#if __has_builtin(__builtin_amdgcn_exp2f)
  return __builtin_amdgcn_exp2f(x);
#else
  return exp2f(x);
#endif
}
__device__ inline float b2f(unsigned short u) {
  return __builtin_bit_cast(float, (unsigned)u << 16);
}
__device__ inline unsigned pack2(float a, float b) {
  unsigned short ua = __builtin_bit_cast(unsigned short, (bf16_t)a);
  unsigned short ub = __builtin_bit_cast(unsigned short, (bf16_t)b);
  return (unsigned)ua | ((unsigned)ub << 16);
}

// ---------------- one-launch cast of Wq,Wk,Wv,Wfc + rel ----------------------
__global__ __launch_bounds__(256) void k_castw(
    const float* __restrict__ s0, const float* __restrict__ s1,
    const float* __restrict__ s2, const float* __restrict__ s3,
    const float* __restrict__ s4, bf16_t* __restrict__ d0,
    bf16_t* __restrict__ d1, bf16_t* __restrict__ d2, bf16_t* __restrict__ d3,
    bf16_t* __restrict__ d4) {
  const int y = blockIdx.y;
  const float* s = y == 0 ? s0 : y == 1 ? s1 : y == 2 ? s2 : y == 3 ? s3 : s4;
  bf16_t* d = y == 0 ? d0 : y == 1 ? d1 : y == 2 ? d2 : y == 3 ? d3 : d4;
  const int n = y < 4 ? Dm * Dm : NREL * DKd;
  int i = (blockIdx.x * 256 + threadIdx.x) * 4;
  if (i + 3 < n) {
    float4 v = *reinterpret_cast<const float4*>(s + i);
    d[i + 0] = (bf16_t)v.x;
    d[i + 1] = (bf16_t)v.y;
    d[i + 2] = (bf16_t)v.z;
    d[i + 3] = (bf16_t)v.w;
  } else if (i < n) {
    for (; i < n; ++i) d[i] = (bf16_t)s[i];
  }
}

// ---------------- one-launch cast of q,k,v (4194304 elems each) --------------
__global__ __launch_bounds__(256) void k_castx(
    const float* __restrict__ s0, const float* __restrict__ s1,
    const float* __restrict__ s2, bf16_t* __restrict__ d0,
    bf16_t* __restrict__ d1, bf16_t* __restrict__ d2) {
  const int y = blockIdx.y;
  const float* s = y == 0 ? s0 : y == 1 ? s1 : s2;
  bf16_t* d = y == 0 ? d0 : y == 1 ? d1 : d2;
  const int i = (blockIdx.x * 256 + threadIdx.x) * 4;
  float4 v = *reinterpret_cast<const float4*>(s + i);
  d[i + 0] = (bf16_t)v.x;
  d[i + 1] = (bf16_t)v.y;
  d[i + 2] = (bf16_t)v.z;
  d[i + 3] = (bf16_t)v.w;
}

// ---------------- y = A @ W^T  (A:[8192][512] bf16, W:[512][512] bf16) --------
// MODE 0: bf16 head-major; MODE 1: bf16 head-transposed.
template <int MODE>
__global__ __launch_bounds__(256) void k_gemm512(const bf16_t* __restrict__ A,
                                                 const bf16_t* __restrict__ W,
                                                 bf16_t* __restrict__ outb) {
  const int lane = threadIdx.x & 63, w = threadIdx.x >> 6;
  const int lr = lane & 15, lg = lane >> 4;
  // bijective chunked XCD swizzle (nwg=1024, chunk=128)
  const int orig = blockIdx.x + blockIdx.y * 8;
  const int swz = ((orig & 7) << 7) | (orig >> 3);
  const int Rbase = (swz >> 3) * 64 + (w >> 1) * 32;
  const int Cbase = (swz & 7) * 64 + (w & 1) * 32;

  f32x4 acc[2][2] = {};
  for (int k0 = 0; k0 < Dm; k0 += 32) {
    bf16x8 af[2], wf[2];
#pragma unroll
    for (int i = 0; i < 2; ++i)
      af[i] = *reinterpret_cast<const bf16x8*>(A + (size_t)(Rbase + i * 16 + lr) * Dm + k0 + lg * 8);
#pragma unroll
    for (int j = 0; j < 2; ++j)
      wf[j] = *reinterpret_cast<const bf16x8*>(W + (size_t)(Cbase + j * 16 + lr) * Dm + k0 + lg * 8);
#pragma unroll
    for (int i = 0; i < 2; ++i)
#pragma unroll
      for (int j = 0; j < 2; ++j)
        acc[i][j] = __builtin_amdgcn_mfma_f32_16x16x32_bf16(af[i], wf[j], acc[i][j], 0, 0, 0);
  }
#pragma unroll
  for (int i = 0; i < 2; ++i)
#pragma unroll
    for (int j = 0; j < 2; ++j)
#pragma unroll
      for (int r = 0; r < 4; ++r) {
        const int gr = Rbase + i * 16 + lg * 4 + r;  // token row
        const int gc = Cbase + j * 16 + lr;          // output col
        const int bb = gr >> 10, qq = gr & 1023, hh = gc >> 6, dd = gc & 63;
        const bf16_t vv = (bf16_t)acc[i][j][r];
        if (MODE == 0)
          outb[(((size_t)(bb * Hh + hh)) * Lseq + qq) * DKd + dd] = vv;
        else
          outb[(((size_t)(bb * Hh + hh)) * DKd + dd) * Lseq + qq] = vv;
      }
}

// ---------------- flash attention + fused in-block posdot ---------------------
// 4-way k-split, LDS pos table (r13-proven). posdot now computed IN-BLOCK via
// MFMA (qf doubles as the A-operand; rel_emb is L2-resident): 52 MFMA/block on
// a 7%-busy MFMA pipe replaces the posd global round-trip (26MB w + 26MB r)
// and the separate kernel. pls[q][j] = POS_C*dot(Q[q],rel[200-j]) (reversed).
__global__ __launch_bounds__(256, 4) void k_attn(const bf16_t* __restrict__ Qh,
                                                 const bf16_t* __restrict__ Kh,
                                                 const bf16_t* __restrict__ Vt,
                                                 const bf16_t* __restrict__ relb,
                                                 bf16_t* __restrict__ attnb) {
  __shared__ float smemf[6528];   // pos 12928B + Pl 10240B = 23168B; Ml 26112B

  const int tid = threadIdx.x;
  const int wv = tid >> 6, lane = tid & 63;
  const int lr = lane & 15, lg = lane >> 4;
  // bijective chunked XCD swizzle (nwg=2048, chunk=256)
  const int gid = ((blockIdx.x & 7) << 8) | (blockIdx.x >> 3);
  const int bh = gid >> 5;
  const int qb = (gid & 31) << 5;             // 32-row q tile

  unsigned short* pls = reinterpret_cast<unsigned short*>(smemf);     // [32][202]
  unsigned* Pw = reinterpret_cast<unsigned*>(smemf) + 3232 + wv * 640; // [2][16][20]

  const bf16_t* Qp = Qh + ((size_t)bh * Lseq + qb) * DKd;
  const bf16_t* Kp = Kh + (size_t)bh * Lseq * DKd;
  const bf16_t* Vp = Vt + (size_t)bh * DKd * Lseq;

  // Q fragments (dual-use: B-operand for swapped QK^T, A-operand for posdot)
  bf16x8 qf[2][2];
#pragma unroll
  for (int t = 0; t < 2; ++t)
#pragma unroll
    for (int h = 0; h < 2; ++h)
      qf[t][h] = *reinterpret_cast<const bf16x8*>(Qp + (size_t)(t * 16 + lr) * DKd + h * 32 + lg * 8);

  // ---- in-block posdot: pls[q][200-r] = POS_C * dot(Q[q], rel[r]) -----------
  // wave wv handles rel-tiles n = wv, wv+4, wv+8, (wv+12 if <13)
  for (int n = wv; n < 13; n += 4) {
    const int rr0 = n * 16 + lr;
    const int rclamp = rr0 > 200 ? 200 : rr0;
    bf16x8 rf0 = *reinterpret_cast<const bf16x8*>(relb + (size_t)rclamp * DKd + lg * 8);
    bf16x8 rf1 = *reinterpret_cast<const bf16x8*>(relb + (size_t)rclamp * DKd + 32 + lg * 8);
#pragma unroll
    for (int t = 0; t < 2; ++t) {
      f32x4 st = {};
      st = __builtin_amdgcn_mfma_f32_16x16x32_bf16(qf[t][0], rf0, st, 0, 0, 0);
      st = __builtin_amdgcn_mfma_f32_16x16x32_bf16(qf[t][1], rf1, st, 0, 0, 0);
      // D: col = lane&15 -> rel index n*16+lr, row = lg*4+reg -> q row
      if (rr0 <= 200) {
#pragma unroll
        for (int r = 0; r < 4; ++r)
          pls[(t * 16 + lg * 4 + r) * PROW + (200 - rr0)] =
              __builtin_bit_cast(unsigned short, (bf16_t)(st[r] * POS_C));
      }
    }
  }
  __syncthreads();

  // per-lane pos row bases + band-edge constants (already scaled by POS_C)
  const unsigned short* prow[2] = {pls + (size_t)lr * PROW,
                                   pls + (size_t)(16 + lr) * PROW};
  float pe0[2], pe200[2];
#pragma unroll
  for (int t = 0; t < 2; ++t) {
    pe0[t] = b2f(prow[t][0]);       // k <= q-100 side
    pe200[t] = b2f(prow[t][200]);   // k >= q+100 side
  }

  f32x4 Oacc[2][4] = {};
  float psum[2] = {0.f, 0.f};
  const int ldelta = lg * 4 - lr;

  const int kbase = wv * 256;
#pragma unroll 2
  for (int k0 = kbase; k0 < kbase + 256; k0 += 32) {
    // K fragments (A-operand: lane&15 = k row, lg*8 = d dims)
    bf16x8 kf[2][2];
#pragma unroll
    for (int u = 0; u < 2; ++u)
#pragma unroll
      for (int h = 0; h < 2; ++h)
        kf[u][h] = *reinterpret_cast<const bf16x8*>(Kp + (size_t)(k0 + u * 16 + lr) * DKd + h * 32 + lg * 8);

#pragma unroll
    for (int t = 0; t < 2; ++t) {
      const int Qt = qb + t * 16;
      f32x4 st[2];
#pragma unroll
      for (int u = 0; u < 2; ++u) {
        f32x4 a = {};
        a = __builtin_amdgcn_mfma_f32_16x16x32_bf16(kf[u][0], qf[t][0], a, 0, 0, 0);
        a = __builtin_amdgcn_mfma_f32_16x16x32_bf16(kf[u][1], qf[t][1], a, 0, 0, 0);
        st[u] = a;  // element: q = Qt+lr (col), k = k0+u*16+lg*4+r (row)
      }
      float p[2][4];
      if (k0 + 131 <= Qt) {            // whole step below band: pos = pls[q][0]
#pragma unroll
        for (int u = 0; u < 2; ++u)
#pragma unroll
          for (int r = 0; r < 4; ++r)
            p[u][r] = fexp2(fmaf(st[u][r], POS_C, pe0[t]));
      } else if (k0 >= Qt + 115) {     // whole step above band: pos = pls[q][200]
#pragma unroll
        for (int u = 0; u < 2; ++u)
#pragma unroll
          for (int r = 0; r < 4; ++r)
            p[u][r] = fexp2(fmaf(st[u][r], POS_C, pe200[t]));
      } else {                         // in-band: clamped gather from LDS
#pragma unroll
        for (int u = 0; u < 2; ++u) {
          const int jb = k0 + u * 16 + 100 - Qt + ldelta;
#pragma unroll
          for (int r = 0; r < 4; ++r) {
            int j = jb + r;
            j = j < 0 ? 0 : (j > 200 ? 200 : j);
            p[u][r] = fexp2(fmaf(st[u][r], POS_C, b2f(prow[t][j])));
          }
        }
      }
#pragma unroll
      for (int u = 0; u < 2; ++u)
#pragma unroll
        for (int r = 0; r < 4; ++r) psum[t] += p[u][r];
      // pack to bf16, wave-private LDS transpose (D-layout -> B-frag layout)
#pragma unroll
      for (int u = 0; u < 2; ++u) {
        uint2 pk;
        pk.x = pack2(p[u][0], p[u][1]);
        pk.y = pack2(p[u][2], p[u][3]);
        *reinterpret_cast<uint2*>(&Pw[t * 320 + lr * 20 + u * 8 + lg * 2]) = pk;
      }
    }
    // PV: A = Vt fragment, B = P fragment read back from LDS
    bf16x8 pb[2];
#pragma unroll
    for (int t = 0; t < 2; ++t)
      pb[t] = *reinterpret_cast<const bf16x8*>(&Pw[t * 320 + lr * 20 + lg * 4]);
#pragma unroll
    for (int f = 0; f < 4; ++f) {
      bf16x8 vf = *reinterpret_cast<const bf16x8*>(Vp + (size_t)(f * 16 + lr) * Lseq + k0 + lg * 8);
#pragma unroll
      for (int t = 0; t < 2; ++t)
        Oacc[t][f] = __builtin_amdgcn_mfma_f32_16x16x32_bf16(vf, pb[t], Oacc[t][f], 0, 0, 0);
    }
  }

  // ---- merge the four k-quarters (no-max partials combine by pure addition) --
  __syncthreads();   // k-loops done; pos+Pl dead -> reuse smem as Ml[3][64][34]
  float* Ml = smemf;
  if (wv) {
    float* m = Ml + ((wv - 1) * 64 + lane) * 34;
#pragma unroll
    for (int t = 0; t < 2; ++t)
#pragma unroll
      for (int f = 0; f < 4; ++f)
#pragma unroll
        for (int r = 0; r < 4; ++r) m[t * 16 + f * 4 + r] = Oacc[t][f][r];
    m[32] = psum[0];
    m[33] = psum[1];
  }
  __syncthreads();
  if (!wv) {
#pragma unroll
    for (int w2 = 0; w2 < 3; ++w2) {
      const float* m = Ml + (w2 * 64 + lane) * 34;
#pragma unroll
      for (int t = 0; t < 2; ++t) {
#pragma unroll
        for (int f = 0; f < 4; ++f)
#pragma unroll
          for (int r = 0; r < 4; ++r) Oacc[t][f][r] += m[t * 16 + f * 4 + r];
        psum[t] += m[32 + t];
      }
    }
    const int gb = bh >> 3, hh = bh & 7;
#pragma unroll
    for (int t = 0; t < 2; ++t) {
      float s = psum[t];
      s += __shfl_xor(s, 16);
      s += __shfl_xor(s, 32);
      const float inv = 1.0f / s;
      const int qg = qb + t * 16 + lr;
#pragma unroll
      for (int f = 0; f < 4; ++f) {
        uint2 ov;
        ov.x = pack2(Oacc[t][f][0] * inv, Oacc[t][f][1] * inv);
        ov.y = pack2(Oacc[t][f][2] * inv, Oacc[t][f][3] * inv);
        *reinterpret_cast<uint2*>(attnb + ((size_t)(gb * Lseq + qg)) * Dm + hh * DKd + f * 16 + lg * 4) = ov;
      }
    }
  }
}

// ---------------- fused fc GEMM + residual + LayerNorm ------------------------
// Block = 16 token rows x full 512 cols (4 waves x 128 cols). In-block row
// reduction kills the 32MB yf round-trip + the separate ln kernel.
__global__ __launch_bounds__(256) void k_fcln(const bf16_t* __restrict__ A,
                                              const bf16_t* __restrict__ W,
                                              const float* __restrict__ resid,
                                              const float* __restrict__ g,
                                              const float* __restrict__ be,
                                              float* __restrict__ out) {
  __shared__ float Ls[16][4], Ls2[16][4];
  const int lane = threadIdx.x & 63, wv = threadIdx.x >> 6;
  const int lr = lane & 15, lg = lane >> 4;
  const int row0 = blockIdx.x * 16;
  const int c0 = wv * 128;

  f32x4 acc[8] = {};
  for (int k0 = 0; k0 < Dm; k0 += 32) {
    bf16x8 af = *reinterpret_cast<const bf16x8*>(A + (size_t)(row0 + lr) * Dm + k0 + lg * 8);
#pragma unroll
    for (int j = 0; j < 8; ++j) {
      bf16x8 wf = *reinterpret_cast<const bf16x8*>(W + (size_t)(c0 + j * 16 + lr) * Dm + k0 + lg * 8);
      acc[j] = __builtin_amdgcn_mfma_f32_16x16x32_bf16(af, wf, acc[j], 0, 0, 0);
    }
  }
  // x = acc + resid; per-row stats (row = lg*4+r local)
  float s[4] = {}, s2[4] = {};
#pragma unroll
  for (int j = 0; j < 8; ++j)
#pragma unroll
    for (int r = 0; r < 4; ++r) {
      const float xv = acc[j][r] +
          resid[(size_t)(row0 + lg * 4 + r) * Dm + c0 + j * 16 + lr];
      acc[j][r] = xv;
      s[r] += xv;
      s2[r] += xv * xv;
    }
#pragma unroll
  for (int r = 0; r < 4; ++r)
#pragma unroll
    for (int mk = 1; mk < 16; mk <<= 1) {
      s[r] += __shfl_xor(s[r], mk, 16);
      s2[r] += __shfl_xor(s2[r], mk, 16);
    }
  if (lr == 0) {
#pragma unroll
    for (int r = 0; r < 4; ++r) {
      Ls[lg * 4 + r][wv] = s[r];
      Ls2[lg * 4 + r][wv] = s2[r];
    }
  }
  __syncthreads();
#pragma unroll
  for (int r = 0; r < 4; ++r) {
    const int row = lg * 4 + r;
    const float S = Ls[row][0] + Ls[row][1] + Ls[row][2] + Ls[row][3];
    const float S2 = Ls2[row][0] + Ls2[row][1] + Ls2[row][2] + Ls2[row][3];
    const float mu = S * (1.0f / Dm);
    const float var = S2 * (1.0f / Dm) - mu * mu;
    const float inv = rsqrtf(var + 1e-6f);
#pragma unroll
    for (int j = 0; j < 8; ++j) {
      const int col = c0 + j * 16 + lr;
      out[(size_t)(row0 + row) * Dm + col] =
          (acc[j][r] - mu) * inv * g[col] + be[col];
    }
  }
}

// ------------------------------------------------------------------------------
extern "C" void kernel_launch(void* const* d_in, const int* in_sizes, int n_in,
                              void* d_out, int out_size, void* d_ws, size_t ws_size,
                              hipStream_t stream) {
  const float* q   = (const float*)d_in[0];
  const float* k   = (const float*)d_in[1];
  const float* v   = (const float*)d_in[2];
  const float* Wq  = (const float*)d_in[3];
  const float* Wk  = (const float*)d_in[4];
  const float* Wv  = (const float*)d_in[5];
  const float* Wfc = (const float*)d_in[6];
  const float* rel = (const float*)d_in[7];
  const float* gam = (const float*)d_in[8];
  const float* bet = (const float*)d_in[9];

  char* ws = (char*)d_ws;
  size_t off = 0;
  auto take = [&](size_t bytes) {
    char* p = ws + off;
    off += (bytes + 255) & ~(size_t)255;
    return p;
  };
  bf16_t* wqb  = (bf16_t*)take((size_t)Dm * Dm * 2);
  bf16_t* wkb  = (bf16_t*)take((size_t)Dm * Dm * 2);
  bf16_t* wvb  = (bf16_t*)take((size_t)Dm * Dm * 2);
  bf16_t* wfcb = (bf16_t*)take((size_t)Dm * Dm * 2);
  bf16_t* relb = (bf16_t*)take((size_t)NREL * DKd * 2);
  bf16_t* qb   = (bf16_t*)take((size_t)MTOK * Dm * 2);
  bf16_t* kb   = (bf16_t*)take((size_t)MTOK * Dm * 2);
  bf16_t* vb   = (bf16_t*)take((size_t)MTOK * Dm * 2);
  bf16_t* Qhp  = (bf16_t*)take((size_t)MTOK * Dm * 2);
  bf16_t* Khp  = (bf16_t*)take((size_t)MTOK * Dm * 2);
  bf16_t* Vtp  = (bf16_t*)take((size_t)MTOK * Dm * 2);
  bf16_t* attnb= (bf16_t*)take((size_t)MTOK * Dm * 2);

  // 1) weights + rel cast (one launch)
  k_castw<<<dim3(Dm * Dm / 1024, 5), 256, 0, stream>>>(
      Wq, Wk, Wv, Wfc, rel, wqb, wkb, wvb, wfcb, relb);
  // 2) q/k/v cast (one launch)
  k_castx<<<dim3(MTOK * Dm / 1024, 3), 256, 0, stream>>>(
      q, k, v, qb, kb, vb);
  // 3) projections
  dim3 gg(Dm / 64, MTOK / 64);
  k_gemm512<0><<<gg, 256, 0, stream>>>(qb, wqb, Qhp);
  k_gemm512<0><<<gg, 256, 0, stream>>>(kb, wkb, Khp);
  k_gemm512<1><<<gg, 256, 0, stream>>>(vb, wvb, Vtp);
  // 4) attention (posdot fused in-block)
  k_attn<<<dim3(2048), 256, 0, stream>>>(Qhp, Khp, Vtp, relb, attnb);
  // 5) output GEMM + residual + LayerNorm (fused)
  k_fcln<<<dim3(MTOK / 16), 256, 0, stream>>>(attnb, wfcb, q, gam, bet,
                                              (float*)d_out);
}